// Round 2
// baseline (2107.576 us; speedup 1.0000x reference)
//
#include <hip/hip_runtime.h>
#include <hip/hip_bf16.h>
#include <stdint.h>

#define SEQ     4096
#define DMODEL  2048
#define NHEADS  16
#define DHEAD   128
#define QBLK    128
#define NWAVES  8
#define CHUNK   128
#define NCHUNK  (SEQ / CHUNK)

typedef __bf16 bf16_t;
typedef bf16_t bf16x8 __attribute__((ext_vector_type(8)));
typedef bf16_t bf16x4 __attribute__((ext_vector_type(4)));
typedef float  f32x4  __attribute__((ext_vector_type(4)));

// byte-offset into a [row][128] bf16 tile (256B rows), XOR-swizzled over 16x16B slots
__device__ __forceinline__ uint32_t swz(int row, int colbyte) {
  return ((uint32_t)(row * 256 + colbyte)) ^ ((uint32_t)(row & 15) << 4);
}

// Flash attention, faithful to the reference quirks:
//   - total score scale = 1/128 (pre-scale * post-divide)
//   - p = exp(s - m_chunk)   [chunk-local max over exactly 128 keys]
//   - o,l rescaled by exp(m_run_old - m_new); out = o / (l + 1e-6)
// Chunks of 128 keys processed strictly in order 0..31.
__global__ __launch_bounds__(512, 4)
void fa_fwd(const float* __restrict__ qg, const float* __restrict__ kg,
            const float* __restrict__ vg, float* __restrict__ og)
{
  __shared__ bf16_t Kl[CHUNK * DHEAD];  // 32 KB, swizzled [key][dh]; overlaid with P after QK^T
  __shared__ bf16_t Vt[DHEAD * CHUNK];  // 32 KB, swizzled [dh][key] (V transposed)

  const int tid  = threadIdx.x;
  const int wave = tid >> 6;
  const int lane = tid & 63;
  const int l15  = lane & 15;
  const int lhi  = lane >> 4;           // 0..3
  const int b    = blockIdx.z;
  const int h    = blockIdx.y;
  const int qrow0 = blockIdx.x * QBLK + wave * 16;

  // ---- Q fragments, A-operand layout (row = l15, k = lhi*8 + i), scaled by 1/128
  bf16x8 qa[4];
  {
    const float* qp = qg + ((size_t)(b * SEQ + qrow0 + l15)) * DMODEL + h * DHEAD;
    const float sc = 1.0f / 128.0f;
#pragma unroll
    for (int kb = 0; kb < 4; ++kb) {
      const float* p8 = qp + kb * 32 + lhi * 8;
      float4 x0 = *(const float4*)p8;
      float4 x1 = *(const float4*)(p8 + 4);
      bf16x8 a;
      a[0] = (bf16_t)(x0.x * sc); a[1] = (bf16_t)(x0.y * sc);
      a[2] = (bf16_t)(x0.z * sc); a[3] = (bf16_t)(x0.w * sc);
      a[4] = (bf16_t)(x1.x * sc); a[5] = (bf16_t)(x1.y * sc);
      a[6] = (bf16_t)(x1.z * sc); a[7] = (bf16_t)(x1.w * sc);
      qa[kb] = a;
    }
  }

  f32x4 oacc[8];
#pragma unroll
  for (int nt = 0; nt < 8; ++nt) { f32x4 z = {0.f, 0.f, 0.f, 0.f}; oacc[nt] = z; }
  float m_run[4] = {-INFINITY, -INFINITY, -INFINITY, -INFINITY};
  float l_run[4] = {0.f, 0.f, 0.f, 0.f};

  const float* kbp = kg + ((size_t)b * SEQ) * DMODEL + h * DHEAD;
  const float* vbp = vg + ((size_t)b * SEQ) * DMODEL + h * DHEAD;

  const int krow16 = tid >> 5;          // K staging: row within pass (0..15)
  const int kc4    = (tid & 31) * 4;    // K staging: dh col (x4 floats)
  const int vdh    = tid & 127;         // V staging: dh column
  const int vkg    = (tid >> 7) * 8;    // V staging: key sub-block {0,8,16,24}

  for (int c = 0; c < NCHUNK; ++c) {
    const int key0 = c * CHUNK;

    // ---- stage K chunk: bf16 [key][dh], swizzled
#pragma unroll
    for (int pass = 0; pass < 8; ++pass) {
      const int key = pass * 16 + krow16;
      const float4 x = *(const float4*)(kbp + (size_t)(key0 + key) * DMODEL + kc4);
      bf16x4 y;
      y[0] = (bf16_t)x.x; y[1] = (bf16_t)x.y; y[2] = (bf16_t)x.z; y[3] = (bf16_t)x.w;
      *(bf16x4*)((char*)Kl + swz(key, kc4 * 2)) = y;
    }
    // ---- stage V chunk transposed: bf16 [dh][key], swizzled
#pragma unroll
    for (int it = 0; it < 4; ++it) {
      const int kb0 = it * 32 + vkg;
      const float* vp = vbp + (size_t)(key0 + kb0) * DMODEL + vdh;
      bf16x8 y;
#pragma unroll
      for (int j = 0; j < 8; ++j) y[j] = (bf16_t)vp[(size_t)j * DMODEL];
      *(bf16x8*)((char*)Vt + swz(vdh, kb0 * 2)) = y;
    }
    __syncthreads();

    // ---- S = Q K^T   (wave: 16 q-rows x 128 keys; 8 key-tiles x 4 k-steps)
    f32x4 sacc[8];
#pragma unroll
    for (int nt = 0; nt < 8; ++nt) {
      f32x4 acc = {0.f, 0.f, 0.f, 0.f};
      const int key = nt * 16 + l15;
#pragma unroll
      for (int kb = 0; kb < 4; ++kb) {
        bf16x8 bfr = *(const bf16x8*)((const char*)Kl + swz(key, (kb * 32 + lhi * 8) * 2));
        acc = __builtin_amdgcn_mfma_f32_16x16x32_bf16(qa[kb], bfr, acc, 0, 0, 0);
      }
      sacc[nt] = acc;
    }

    // ---- chunk-local row max over 128 keys (reduce 8 tiles, then 16-lane group)
    float mc[4];
#pragma unroll
    for (int r = 0; r < 4; ++r) {
      float m0 = sacc[0][r];
#pragma unroll
      for (int nt = 1; nt < 8; ++nt) m0 = fmaxf(m0, sacc[nt][r]);
      mc[r] = m0;
    }
#pragma unroll
    for (int sh = 1; sh < 16; sh <<= 1)
#pragma unroll
      for (int r = 0; r < 4; ++r)
        mc[r] = fmaxf(mc[r], __shfl_xor(mc[r], sh, 64));

    float esc[4], psum[4];
#pragma unroll
    for (int r = 0; r < 4; ++r) {
      const float mn = fmaxf(m_run[r], mc[r]);
      esc[r] = __expf(m_run[r] - mn);   // exp(-inf)=0 handles first chunk
      m_run[r] = mn;
      psum[r] = 0.f;
    }

    // ---- p = exp(s - m_chunk), row-sum, convert to bf16
    bf16_t pb[32];
#pragma unroll
    for (int nt = 0; nt < 8; ++nt)
#pragma unroll
      for (int r = 0; r < 4; ++r) {
        const float p = __expf(sacc[nt][r] - mc[r]);
        psum[r] += p;
        pb[nt * 4 + r] = (bf16_t)p;
      }
#pragma unroll
    for (int sh = 1; sh < 16; sh <<= 1)
#pragma unroll
      for (int r = 0; r < 4; ++r)
        psum[r] += __shfl_xor(psum[r], sh, 64);
#pragma unroll
    for (int r = 0; r < 4; ++r)
      l_run[r] = l_run[r] * esc[r] + psum[r];
#pragma unroll
    for (int nt = 0; nt < 8; ++nt) {
      f32x4 o = oacc[nt];
      o[0] *= esc[0]; o[1] *= esc[1]; o[2] *= esc[2]; o[3] *= esc[3];
      oacc[nt] = o;
    }

    __syncthreads();  // all waves done reading Kl -> safe to overlay P

    // ---- P -> per-wave LDS slice ([row16][key128], swizzled)
    bf16_t* Pw = Kl + wave * (16 * 128);
#pragma unroll
    for (int nt = 0; nt < 8; ++nt)
#pragma unroll
      for (int r = 0; r < 4; ++r) {
        const int row = lhi * 4 + r;
        *(bf16_t*)((char*)Pw + swz(row, (nt * 16 + l15) * 2)) = pb[nt * 4 + r];
      }
    asm volatile("s_waitcnt lgkmcnt(0)" ::: "memory");  // wave-local write->read ordering
    __builtin_amdgcn_sched_barrier(0);

    // ---- O += P V   (A = P from LDS, B = V^T fragments from Vt)
#pragma unroll
    for (int kb = 0; kb < 4; ++kb) {
      bf16x8 pf = *(const bf16x8*)((const char*)Pw + swz(l15, (kb * 32 + lhi * 8) * 2));
#pragma unroll
      for (int nt = 0; nt < 8; ++nt) {
        const int dh = nt * 16 + l15;
        bf16x8 vf = *(const bf16x8*)((const char*)Vt + swz(dh, (kb * 32 + lhi * 8) * 2));
        oacc[nt] = __builtin_amdgcn_mfma_f32_16x16x32_bf16(pf, vf, oacc[nt], 0, 0, 0);
      }
    }
    __syncthreads();  // before next chunk overwrites Kl/Vt
  }

  // ---- epilogue: out = O / (l + eps)
#pragma unroll
  for (int nt = 0; nt < 8; ++nt)
#pragma unroll
    for (int r = 0; r < 4; ++r) {
      const int row = lhi * 4 + r;
      const float val = oacc[nt][r] / (l_run[r] + 1e-6f);
      og[((size_t)(b * SEQ + qrow0 + row)) * DMODEL + h * DHEAD + nt * 16 + l15] = val;
    }
}

extern "C" void kernel_launch(void* const* d_in, const int* in_sizes, int n_in,
                              void* d_out, int out_size, void* d_ws, size_t ws_size,
                              hipStream_t stream) {
  const float* q = (const float*)d_in[0];
  const float* k = (const float*)d_in[1];
  const float* v = (const float*)d_in[2];
  float* o = (float*)d_out;
  const int B = in_sizes[0] / (SEQ * DMODEL);
  dim3 grid(SEQ / QBLK, NHEADS, B);
  fa_fwd<<<grid, 512, 0, stream>>>(q, k, v, o);
}

// Round 3
// 2026.854 us; speedup vs baseline: 1.0398x; 1.0398x over previous
//
#include <hip/hip_runtime.h>
#include <hip/hip_bf16.h>
#include <stdint.h>

#define SEQ     4096
#define DMODEL  2048
#define NHEADS  16
#define DHEAD   128
#define QBLK    128
#define CHUNK   128
#define NCHUNK  (SEQ / CHUNK)

typedef __bf16 bf16_t;
typedef bf16_t bf16x8 __attribute__((ext_vector_type(8)));
typedef bf16_t bf16x4 __attribute__((ext_vector_type(4)));
typedef float  f32x4  __attribute__((ext_vector_type(4)));

// byte-offset into a [row][128] bf16 tile (256B rows), XOR-swizzled over 16x16B slots
__device__ __forceinline__ uint32_t swz(int row, int colbyte) {
  return ((uint32_t)(row * 256 + colbyte)) ^ ((uint32_t)(row & 15) << 4);
}

// barrier that does NOT drain vmcnt: prefetch loads stay in flight
#define BAR() asm volatile("s_waitcnt lgkmcnt(0)\n\ts_barrier" ::: "memory")

// ---------------- prepass: K -> bf16 head-major [bh][s][128] ----------------
__global__ __launch_bounds__(256)
void prep_k(const float* __restrict__ kk, bf16_t* __restrict__ kb) {
  const size_t e = ((size_t)blockIdx.x * 256 + threadIdx.x) * 8;
  const int dm = (int)(e % DMODEL);
  const int s  = (int)((e / DMODEL) % SEQ);
  const int b  = (int)(e / ((size_t)DMODEL * SEQ));
  float4 x0 = *(const float4*)(kk + e);
  float4 x1 = *(const float4*)(kk + e + 4);
  bf16x8 y;
  y[0]=(bf16_t)x0.x; y[1]=(bf16_t)x0.y; y[2]=(bf16_t)x0.z; y[3]=(bf16_t)x0.w;
  y[4]=(bf16_t)x1.x; y[5]=(bf16_t)x1.y; y[6]=(bf16_t)x1.z; y[7]=(bf16_t)x1.w;
  const size_t out = (((size_t)(b * NHEADS + (dm >> 7)) * SEQ + s) << 7) + (dm & 127);
  *(bf16x8*)(kb + out) = y;
}

// ---------------- prepass: V -> bf16 transposed [bh][dh][s] ----------------
__global__ __launch_bounds__(256)
void prep_v(const float* __restrict__ vv, bf16_t* __restrict__ vb) {
  __shared__ bf16_t T[128 * 132];   // +4 bf16 pad: strided reads ~2-way only
  const int t = threadIdx.x;
  const int s0 = blockIdx.x * 128, h = blockIdx.y, b = blockIdx.z;
  const float* src = vv + ((size_t)(b * SEQ + s0)) * DMODEL + h * DHEAD;
#pragma unroll
  for (int p = 0; p < 16; ++p) {
    const int sr = p * 8 + (t >> 5), c4 = (t & 31) * 4;
    float4 x = *(const float4*)(src + (size_t)sr * DMODEL + c4);
    bf16_t* d = T + sr * 132 + c4;
    d[0]=(bf16_t)x.x; d[1]=(bf16_t)x.y; d[2]=(bf16_t)x.z; d[3]=(bf16_t)x.w;
  }
  __syncthreads();
  bf16_t* out = vb + ((size_t)(b * NHEADS + h)) * DHEAD * SEQ;
#pragma unroll
  for (int p = 0; p < 8; ++p) {
    const int d = p * 16 + (t >> 4), sc8 = (t & 15) * 8;
    bf16x8 y;
#pragma unroll
    for (int j = 0; j < 8; ++j) y[j] = T[(sc8 + j) * 132 + d];
    *(bf16x8*)(out + (size_t)d * SEQ + s0 + sc8) = y;
  }
}

// ---------------- main: pipelined flash attention on prepped K/V ----------------
// Faithful reference quirks: total scale 1/128; p = exp(s - m_chunk) with
// chunk-local max over exactly 128 keys; o,l rescaled by exp(m_old-m_new);
// out = o/(l+1e-6). Chunks processed strictly in order.
__global__ __launch_bounds__(512, 4)
void fa_fwd_p(const float* __restrict__ qg, const bf16_t* __restrict__ kbg,
              const bf16_t* __restrict__ vbg, float* __restrict__ og)
{
  __shared__ char smem[65536];
  bf16_t* Kl = (bf16_t*)smem;            // 32KB [key][dh] swizzled; P overlays after QK
  bf16_t* Vt = (bf16_t*)(smem + 32768);  // 32KB [dh][key] swizzled

  const int tid  = threadIdx.x;
  const int wave = tid >> 6;
  const int lane = tid & 63;
  const int l15  = lane & 15;
  const int lhi  = lane >> 4;

  // T1: bijective XCD swizzle of the flat workgroup id (nwg = 32*16*B, %8==0)
  const int nwg = gridDim.x * gridDim.y * gridDim.z;
  const int lin = blockIdx.x + gridDim.x * (blockIdx.y + gridDim.y * blockIdx.z);
  const int wg  = (lin % 8) * (nwg / 8) + lin / 8;
  const int bx  = wg % gridDim.x;
  const int h   = (wg / gridDim.x) % NHEADS;
  const int b   = wg / (gridDim.x * NHEADS);
  const int bh  = b * NHEADS + h;
  const int qrow0 = bx * QBLK + wave * 16;

  // ---- Q fragments from f32 global, A-layout (row=l15, k=lhi*8+i), scale 1/128
  bf16x8 qa[4];
  {
    const float* qp = qg + ((size_t)(b * SEQ + qrow0 + l15)) * DMODEL + h * DHEAD;
    const float sc = 1.0f / 128.0f;
#pragma unroll
    for (int kb = 0; kb < 4; ++kb) {
      const float* p8 = qp + kb * 32 + lhi * 8;
      float4 x0 = *(const float4*)p8;
      float4 x1 = *(const float4*)(p8 + 4);
      bf16x8 a;
      a[0] = (bf16_t)(x0.x * sc); a[1] = (bf16_t)(x0.y * sc);
      a[2] = (bf16_t)(x0.z * sc); a[3] = (bf16_t)(x0.w * sc);
      a[4] = (bf16_t)(x1.x * sc); a[5] = (bf16_t)(x1.y * sc);
      a[6] = (bf16_t)(x1.z * sc); a[7] = (bf16_t)(x1.w * sc);
      qa[kb] = a;
    }
  }

  f32x4 oacc[8];
#pragma unroll
  for (int nt = 0; nt < 8; ++nt) { f32x4 z = {0.f,0.f,0.f,0.f}; oacc[nt] = z; }
  float m_run[4] = {-INFINITY, -INFINITY, -INFINITY, -INFINITY};
  float l_run[4] = {0.f, 0.f, 0.f, 0.f};

  const bf16_t* kcb = kbg + ((size_t)bh * SEQ) * DHEAD;   // [key][128] contiguous
  const bf16_t* vcb = vbg + ((size_t)bh * DHEAD) * SEQ;   // [dh][SEQ]

  bf16x8 kr[4], vr[4];   // T14 register staging (+32 VGPR)
#define LOADC(c)                                                              \
  {                                                                           \
    const bf16_t* kc = kcb + (size_t)(c) * CHUNK * DHEAD;                     \
    _Pragma("unroll")                                                         \
    for (int p = 0; p < 4; ++p)                                               \
      kr[p] = *(const bf16x8*)((const char*)kc + p * 8192 + tid * 16);        \
    const bf16_t* vc = vcb + (size_t)(c) * CHUNK;                             \
    _Pragma("unroll")                                                         \
    for (int p = 0; p < 4; ++p) {                                             \
      const int dh = p * 32 + (tid >> 4);                                     \
      vr[p] = *(const bf16x8*)((const char*)vc + (size_t)dh * SEQ * 2 +       \
                               (tid & 15) * 16);                              \
    }                                                                         \
  }

  LOADC(0);

  for (int c = 0; c < NCHUNK; ++c) {
    BAR();  // previous chunk's LDS reads fully consumed

    // ---- ds_write staged chunk (swizzled); compiler inserts vmcnt wait here
#pragma unroll
    for (int p = 0; p < 4; ++p) {
      const int o = p * 8192 + tid * 16;
      *(bf16x8*)((char*)Kl + swz(o >> 8, o & 255)) = kr[p];
    }
#pragma unroll
    for (int p = 0; p < 4; ++p) {
      const int dh = p * 32 + (tid >> 4);
      *(bf16x8*)((char*)Vt + swz(dh, (tid & 15) * 16)) = vr[p];
    }
    BAR();  // staged (lgkm only; vmcnt untouched)

    if (c + 1 < NCHUNK) LOADC(c + 1);  // prefetch in flight across QK+softmax+PV

    // ---- S = Q K^T
    f32x4 sacc[8];
    __builtin_amdgcn_s_setprio(1);
#pragma unroll
    for (int nt = 0; nt < 8; ++nt) {
      f32x4 acc = {0.f, 0.f, 0.f, 0.f};
      const int key = nt * 16 + l15;
#pragma unroll
      for (int kb = 0; kb < 4; ++kb) {
        bf16x8 bfr = *(const bf16x8*)((const char*)Kl + swz(key, kb * 64 + lhi * 16));
        acc = __builtin_amdgcn_mfma_f32_16x16x32_bf16(qa[kb], bfr, acc, 0, 0, 0);
      }
      sacc[nt] = acc;
    }
    __builtin_amdgcn_s_setprio(0);

    // ---- chunk-local row max over 128 keys
    float mc[4];
#pragma unroll
    for (int r = 0; r < 4; ++r) {
      float m0 = sacc[0][r];
#pragma unroll
      for (int nt = 1; nt < 8; ++nt) m0 = fmaxf(m0, sacc[nt][r]);
      mc[r] = m0;
    }
#pragma unroll
    for (int sh = 1; sh < 16; sh <<= 1)
#pragma unroll
      for (int r = 0; r < 4; ++r)
        mc[r] = fmaxf(mc[r], __shfl_xor(mc[r], sh, 64));

    float esc[4], psum[4];
#pragma unroll
    for (int r = 0; r < 4; ++r) {
      const float mn = fmaxf(m_run[r], mc[r]);
      esc[r] = __expf(m_run[r] - mn);
      m_run[r] = mn;
      psum[r] = 0.f;
    }

    bf16_t pb[32];
#pragma unroll
    for (int nt = 0; nt < 8; ++nt)
#pragma unroll
      for (int r = 0; r < 4; ++r) {
        const float p = __expf(sacc[nt][r] - mc[r]);
        psum[r] += p;
        pb[nt * 4 + r] = (bf16_t)p;
      }
#pragma unroll
    for (int sh = 1; sh < 16; sh <<= 1)
#pragma unroll
      for (int r = 0; r < 4; ++r)
        psum[r] += __shfl_xor(psum[r], sh, 64);
#pragma unroll
    for (int r = 0; r < 4; ++r)
      l_run[r] = l_run[r] * esc[r] + psum[r];
#pragma unroll
    for (int nt = 0; nt < 8; ++nt) {
      f32x4 o = oacc[nt];
      o[0] *= esc[0]; o[1] *= esc[1]; o[2] *= esc[2]; o[3] *= esc[3];
      oacc[nt] = o;
    }

    BAR();  // all waves done reading Kl -> safe to overlay P

    // ---- P -> per-wave 4KB slice of Kl ([row16][key128], swizzled)
    bf16_t* Pw = Kl + wave * (16 * 128);
#pragma unroll
    for (int nt = 0; nt < 8; ++nt)
#pragma unroll
      for (int r = 0; r < 4; ++r) {
        const int row = lhi * 4 + r;
        *(bf16_t*)((char*)Pw + swz(row, (nt * 16 + l15) * 2)) = pb[nt * 4 + r];
      }
    asm volatile("s_waitcnt lgkmcnt(0)" ::: "memory");
    __builtin_amdgcn_sched_barrier(0);

    // ---- O += P V
    __builtin_amdgcn_s_setprio(1);
#pragma unroll
    for (int kb = 0; kb < 4; ++kb) {
      bf16x8 pf = *(const bf16x8*)((const char*)Pw + swz(l15, kb * 64 + lhi * 16));
#pragma unroll
      for (int nt = 0; nt < 8; ++nt) {
        const int dh = nt * 16 + l15;
        bf16x8 vf = *(const bf16x8*)((const char*)Vt + swz(dh, kb * 64 + lhi * 16));
        oacc[nt] = __builtin_amdgcn_mfma_f32_16x16x32_bf16(pf, vf, oacc[nt], 0, 0, 0);
      }
    }
    __builtin_amdgcn_s_setprio(0);
  }

  // ---- epilogue: per-wave LDS transpose -> coalesced f32x4 stores
  BAR();  // all PV reads of Kl/Vt done; smem reusable
  {
    char* Ow = smem + wave * 8192;  // 16 rows x 512B
#pragma unroll
    for (int nt = 0; nt < 8; ++nt)
#pragma unroll
      for (int r = 0; r < 4; ++r) {
        const int row = lhi * 4 + r;
        const int colb = (nt * 16 + l15) * 4;
        *(float*)(Ow + row * 512 + (colb ^ ((row & 7) << 4))) =
            oacc[nt][r] / (l_run[r] + 1e-6f);
      }
    asm volatile("s_waitcnt lgkmcnt(0)" ::: "memory");  // wave-local only
    __builtin_amdgcn_sched_barrier(0);
#pragma unroll
    for (int p = 0; p < 8; ++p) {
      const int row = p * 2 + (lane >> 5);
      const int colb = (lane & 31) * 16;
      f32x4 val = *(const f32x4*)(Ow + row * 512 + (colb ^ ((row & 7) << 4)));
      *(f32x4*)((char*)(og + ((size_t)(b * SEQ + qrow0 + row)) * DMODEL + h * DHEAD) + colb) = val;
    }
  }
}

// ---------------- fallback (R2 kernel, proven): used if ws too small ----------------
__global__ __launch_bounds__(512, 4)
void fa_fwd_raw(const float* __restrict__ qg, const float* __restrict__ kg,
                const float* __restrict__ vg, float* __restrict__ og)
{
  __shared__ bf16_t Kl[CHUNK * DHEAD];
  __shared__ bf16_t Vt[DHEAD * CHUNK];
  const int tid = threadIdx.x, wave = tid >> 6, lane = tid & 63;
  const int l15 = lane & 15, lhi = lane >> 4;
  const int b = blockIdx.z, h = blockIdx.y;
  const int qrow0 = blockIdx.x * QBLK + wave * 16;
  bf16x8 qa[4];
  {
    const float* qp = qg + ((size_t)(b * SEQ + qrow0 + l15)) * DMODEL + h * DHEAD;
    const float sc = 1.0f / 128.0f;
#pragma unroll
    for (int kb = 0; kb < 4; ++kb) {
      const float* p8 = qp + kb * 32 + lhi * 8;
      float4 x0 = *(const float4*)p8; float4 x1 = *(const float4*)(p8 + 4);
      bf16x8 a;
      a[0]=(bf16_t)(x0.x*sc); a[1]=(bf16_t)(x0.y*sc); a[2]=(bf16_t)(x0.z*sc); a[3]=(bf16_t)(x0.w*sc);
      a[4]=(bf16_t)(x1.x*sc); a[5]=(bf16_t)(x1.y*sc); a[6]=(bf16_t)(x1.z*sc); a[7]=(bf16_t)(x1.w*sc);
      qa[kb] = a;
    }
  }
  f32x4 oacc[8];
#pragma unroll
  for (int nt = 0; nt < 8; ++nt) { f32x4 z = {0.f,0.f,0.f,0.f}; oacc[nt] = z; }
  float m_run[4] = {-INFINITY,-INFINITY,-INFINITY,-INFINITY};
  float l_run[4] = {0.f,0.f,0.f,0.f};
  const float* kbp = kg + ((size_t)b * SEQ) * DMODEL + h * DHEAD;
  const float* vbp = vg + ((size_t)b * SEQ) * DMODEL + h * DHEAD;
  const int krow16 = tid >> 5, kc4 = (tid & 31) * 4;
  const int vdh = tid & 127, vkg = (tid >> 7) * 8;
  for (int c = 0; c < NCHUNK; ++c) {
    const int key0 = c * CHUNK;
#pragma unroll
    for (int pass = 0; pass < 8; ++pass) {
      const int key = pass * 16 + krow16;
      const float4 x = *(const float4*)(kbp + (size_t)(key0 + key) * DMODEL + kc4);
      bf16x4 y; y[0]=(bf16_t)x.x; y[1]=(bf16_t)x.y; y[2]=(bf16_t)x.z; y[3]=(bf16_t)x.w;
      *(bf16x4*)((char*)Kl + swz(key, kc4 * 2)) = y;
    }
#pragma unroll
    for (int it = 0; it < 4; ++it) {
      const int kb0 = it * 32 + vkg;
      const float* vp = vbp + (size_t)(key0 + kb0) * DMODEL + vdh;
      bf16x8 y;
#pragma unroll
      for (int j = 0; j < 8; ++j) y[j] = (bf16_t)vp[(size_t)j * DMODEL];
      *(bf16x8*)((char*)Vt + swz(vdh, kb0 * 2)) = y;
    }
    __syncthreads();
    f32x4 sacc[8];
#pragma unroll
    for (int nt = 0; nt < 8; ++nt) {
      f32x4 acc = {0.f,0.f,0.f,0.f};
      const int key = nt * 16 + l15;
#pragma unroll
      for (int kb = 0; kb < 4; ++kb) {
        bf16x8 bfr = *(const bf16x8*)((const char*)Kl + swz(key, (kb*32+lhi*8)*2));
        acc = __builtin_amdgcn_mfma_f32_16x16x32_bf16(qa[kb], bfr, acc, 0, 0, 0);
      }
      sacc[nt] = acc;
    }
    float mc[4];
#pragma unroll
    for (int r = 0; r < 4; ++r) {
      float m0 = sacc[0][r];
#pragma unroll
      for (int nt = 1; nt < 8; ++nt) m0 = fmaxf(m0, sacc[nt][r]);
      mc[r] = m0;
    }
#pragma unroll
    for (int sh = 1; sh < 16; sh <<= 1)
#pragma unroll
      for (int r = 0; r < 4; ++r) mc[r] = fmaxf(mc[r], __shfl_xor(mc[r], sh, 64));
    float esc[4], psum[4];
#pragma unroll
    for (int r = 0; r < 4; ++r) {
      const float mn = fmaxf(m_run[r], mc[r]);
      esc[r] = __expf(m_run[r] - mn); m_run[r] = mn; psum[r] = 0.f;
    }
    bf16_t pb[32];
#pragma unroll
    for (int nt = 0; nt < 8; ++nt)
#pragma unroll
      for (int r = 0; r < 4; ++r) {
        const float p = __expf(sacc[nt][r] - mc[r]);
        psum[r] += p; pb[nt*4+r] = (bf16_t)p;
      }
#pragma unroll
    for (int sh = 1; sh < 16; sh <<= 1)
#pragma unroll
      for (int r = 0; r < 4; ++r) psum[r] += __shfl_xor(psum[r], sh, 64);
#pragma unroll
    for (int r = 0; r < 4; ++r) l_run[r] = l_run[r] * esc[r] + psum[r];
#pragma unroll
    for (int nt = 0; nt < 8; ++nt) {
      f32x4 o = oacc[nt];
      o[0]*=esc[0]; o[1]*=esc[1]; o[2]*=esc[2]; o[3]*=esc[3];
      oacc[nt] = o;
    }
    __syncthreads();
    bf16_t* Pw = Kl + wave * (16 * 128);
#pragma unroll
    for (int nt = 0; nt < 8; ++nt)
#pragma unroll
      for (int r = 0; r < 4; ++r) {
        const int row = lhi * 4 + r;
        *(bf16_t*)((char*)Pw + swz(row, (nt*16+l15)*2)) = pb[nt*4+r];
      }
    asm volatile("s_waitcnt lgkmcnt(0)" ::: "memory");
    __builtin_amdgcn_sched_barrier(0);
#pragma unroll
    for (int kb = 0; kb < 4; ++kb) {
      bf16x8 pf = *(const bf16x8*)((const char*)Pw + swz(l15, (kb*32+lhi*8)*2));
#pragma unroll
      for (int nt = 0; nt < 8; ++nt) {
        const int dh = nt * 16 + l15;
        bf16x8 vf = *(const bf16x8*)((const char*)Vt + swz(dh, (kb*32+lhi*8)*2));
        oacc[nt] = __builtin_amdgcn_mfma_f32_16x16x32_bf16(pf, vf, oacc[nt], 0, 0, 0);
      }
    }
    __syncthreads();
  }
#pragma unroll
  for (int nt = 0; nt < 8; ++nt)
#pragma unroll
    for (int r = 0; r < 4; ++r) {
      const int row = lhi * 4 + r;
      og[((size_t)(b * SEQ + qrow0 + row)) * DMODEL + h * DHEAD + nt * 16 + l15] =
          oacc[nt][r] / (l_run[r] + 1e-6f);
    }
}

extern "C" void kernel_launch(void* const* d_in, const int* in_sizes, int n_in,
                              void* d_out, int out_size, void* d_ws, size_t ws_size,
                              hipStream_t stream) {
  const float* q = (const float*)d_in[0];
  const float* k = (const float*)d_in[1];
  const float* v = (const float*)d_in[2];
  float* o = (float*)d_out;
  const int B = in_sizes[0] / (SEQ * DMODEL);
  const size_t kv_bytes = (size_t)B * NHEADS * SEQ * DHEAD * 2;  // 33.5MB @ B=2
  dim3 grid(SEQ / QBLK, NHEADS, B);
  if (ws_size >= 2 * kv_bytes) {
    bf16_t* kb = (bf16_t*)d_ws;
    bf16_t* vb = (bf16_t*)((char*)d_ws + kv_bytes);
    const int nthr = (int)(((size_t)B * SEQ * DMODEL) / 8);
    prep_k<<<nthr / 256, 256, 0, stream>>>(k, kb);
    dim3 gv(SEQ / 128, NHEADS, B);
    prep_v<<<gv, 256, 0, stream>>>(v, vb);
    fa_fwd_p<<<grid, 512, 0, stream>>>(q, kb, vb, o);
  } else {
    fa_fwd_raw<<<grid, 512, 0, stream>>>(q, k, v, o);
  }
}

// Round 4
// 555.022 us; speedup vs baseline: 3.7973x; 3.6518x over previous
//
#include <hip/hip_runtime.h>
#include <hip/hip_bf16.h>
#include <stdint.h>

#define SEQ     4096
#define DMODEL  2048
#define NHEADS  16
#define DHEAD   128
#define QBLK    128
#define CHUNK   128
#define NCHUNK  (SEQ / CHUNK)

typedef __bf16 bf16_t;
typedef bf16_t bf16x8 __attribute__((ext_vector_type(8)));
typedef bf16_t bf16x4 __attribute__((ext_vector_type(4)));
typedef float  f32x4  __attribute__((ext_vector_type(4)));

// byte-offset into a [row][128] bf16 tile (256B rows), XOR-swizzled over 16x16B slots
__device__ __forceinline__ uint32_t swz(int row, int colbyte) {
  return ((uint32_t)(row * 256 + colbyte)) ^ ((uint32_t)(row & 15) << 4);
}

// barrier that does NOT drain vmcnt: prefetch loads stay in flight
#define BAR() asm volatile("s_waitcnt lgkmcnt(0)\n\ts_barrier" ::: "memory")

// ---------------- prepass: K -> bf16 head-major [bh][s][128] ----------------
__global__ __launch_bounds__(256)
void prep_k(const float* __restrict__ kk, bf16_t* __restrict__ kb) {
  const size_t e = ((size_t)blockIdx.x * 256 + threadIdx.x) * 8;
  const int dm = (int)(e % DMODEL);
  const int s  = (int)((e / DMODEL) % SEQ);
  const int b  = (int)(e / ((size_t)DMODEL * SEQ));
  float4 x0 = *(const float4*)(kk + e);
  float4 x1 = *(const float4*)(kk + e + 4);
  bf16x8 y;
  y[0]=(bf16_t)x0.x; y[1]=(bf16_t)x0.y; y[2]=(bf16_t)x0.z; y[3]=(bf16_t)x0.w;
  y[4]=(bf16_t)x1.x; y[5]=(bf16_t)x1.y; y[6]=(bf16_t)x1.z; y[7]=(bf16_t)x1.w;
  const size_t out = (((size_t)(b * NHEADS + (dm >> 7)) * SEQ + s) << 7) + (dm & 127);
  *(bf16x8*)(kb + out) = y;
}

// ---------------- prepass: V -> bf16 transposed [bh][dh][s] ----------------
__global__ __launch_bounds__(256)
void prep_v(const float* __restrict__ vv, bf16_t* __restrict__ vb) {
  __shared__ bf16_t T[128 * 132];   // +4 bf16 pad
  const int t = threadIdx.x;
  const int s0 = blockIdx.x * 128, h = blockIdx.y, b = blockIdx.z;
  const float* src = vv + ((size_t)(b * SEQ + s0)) * DMODEL + h * DHEAD;
#pragma unroll
  for (int p = 0; p < 16; ++p) {
    const int sr = p * 8 + (t >> 5), c4 = (t & 31) * 4;
    float4 x = *(const float4*)(src + (size_t)sr * DMODEL + c4);
    bf16_t* d = T + sr * 132 + c4;
    d[0]=(bf16_t)x.x; d[1]=(bf16_t)x.y; d[2]=(bf16_t)x.z; d[3]=(bf16_t)x.w;
  }
  __syncthreads();
  bf16_t* out = vb + ((size_t)(b * NHEADS + h)) * DHEAD * SEQ;
#pragma unroll
  for (int p = 0; p < 8; ++p) {
    const int d = p * 16 + (t >> 4), sc8 = (t & 15) * 8;
    bf16x8 y;
#pragma unroll
    for (int j = 0; j < 8; ++j) y[j] = T[(sc8 + j) * 132 + d];
    *(bf16x8*)(out + (size_t)d * SEQ + s0 + sc8) = y;
  }
}

// ---------------- main: pipelined flash attention on prepped K/V ----------------
// Faithful reference quirks: total scale 1/128; p = exp(s - m_chunk) with
// chunk-local max over exactly 128 keys; o,l rescaled by exp(m_old-m_new);
// out = o/(l+1e-6). Chunks processed strictly in order.
// launch_bounds(512,2): arg2 is blocks/CU on this backend -> VGPR cap 128
// (R3's (512,4) capped VGPR at 64 -> 3.5GB/dispatch scratch spill traffic).
__global__ __launch_bounds__(512, 2)
void fa_fwd_p(const float* __restrict__ qg, const bf16_t* __restrict__ kbg,
              const bf16_t* __restrict__ vbg, float* __restrict__ og)
{
  __shared__ char smem[65536];
  bf16_t* Kl = (bf16_t*)smem;            // 32KB [key][dh] swizzled; P overlays after QK
  bf16_t* Vt = (bf16_t*)(smem + 32768);  // 32KB [dh][key] swizzled

  const int tid  = threadIdx.x;
  const int wave = tid >> 6;
  const int lane = tid & 63;
  const int l15  = lane & 15;
  const int lhi  = lane >> 4;

  // T1: bijective XCD swizzle of the flat workgroup id (nwg = 32*16*B, %8==0)
  const int nwg = gridDim.x * gridDim.y * gridDim.z;
  const int lin = blockIdx.x + gridDim.x * (blockIdx.y + gridDim.y * blockIdx.z);
  const int wg  = (lin % 8) * (nwg / 8) + lin / 8;
  const int bx  = wg % gridDim.x;
  const int h   = (wg / gridDim.x) % NHEADS;
  const int b   = wg / (gridDim.x * NHEADS);
  const int bh  = b * NHEADS + h;
  const int qrow0 = bx * QBLK + wave * 16;

  // ---- Q fragments from f32 global, A-layout (row=l15, k=lhi*8+i), scale 1/128
  bf16x8 qa[4];
  {
    const float* qp = qg + ((size_t)(b * SEQ + qrow0 + l15)) * DMODEL + h * DHEAD;
    const float sc = 1.0f / 128.0f;
#pragma unroll
    for (int kb = 0; kb < 4; ++kb) {
      const float* p8 = qp + kb * 32 + lhi * 8;
      float4 x0 = *(const float4*)p8;
      float4 x1 = *(const float4*)(p8 + 4);
      bf16x8 a;
      a[0] = (bf16_t)(x0.x * sc); a[1] = (bf16_t)(x0.y * sc);
      a[2] = (bf16_t)(x0.z * sc); a[3] = (bf16_t)(x0.w * sc);
      a[4] = (bf16_t)(x1.x * sc); a[5] = (bf16_t)(x1.y * sc);
      a[6] = (bf16_t)(x1.z * sc); a[7] = (bf16_t)(x1.w * sc);
      qa[kb] = a;
    }
  }

  f32x4 oacc[8];
#pragma unroll
  for (int nt = 0; nt < 8; ++nt) { f32x4 z = {0.f,0.f,0.f,0.f}; oacc[nt] = z; }
  float m_run[4] = {-INFINITY, -INFINITY, -INFINITY, -INFINITY};
  float l_run[4] = {0.f, 0.f, 0.f, 0.f};

  const bf16_t* kcb = kbg + ((size_t)bh * SEQ) * DHEAD;   // [key][128] contiguous
  const bf16_t* vcb = vbg + ((size_t)bh * DHEAD) * SEQ;   // [dh][SEQ]

  bf16x8 kr[4], vr[4];   // T14 register staging (+32 VGPR)
#define LOADC(c)                                                              \
  {                                                                           \
    const bf16_t* kc = kcb + (size_t)(c) * CHUNK * DHEAD;                     \
    _Pragma("unroll")                                                         \
    for (int p = 0; p < 4; ++p)                                               \
      kr[p] = *(const bf16x8*)((const char*)kc + p * 8192 + tid * 16);        \
    const bf16_t* vc = vcb + (size_t)(c) * CHUNK;                             \
    _Pragma("unroll")                                                         \
    for (int p = 0; p < 4; ++p) {                                             \
      const int dh = p * 32 + (tid >> 4);                                     \
      vr[p] = *(const bf16x8*)((const char*)vc + (size_t)dh * SEQ * 2 +       \
                               (tid & 15) * 16);                              \
    }                                                                         \
  }

  LOADC(0);

  for (int c = 0; c < NCHUNK; ++c) {
    BAR();  // previous chunk's LDS reads fully consumed

    // ---- ds_write staged chunk (swizzled); compiler inserts vmcnt wait here
#pragma unroll
    for (int p = 0; p < 4; ++p) {
      const int o = p * 8192 + tid * 16;
      *(bf16x8*)((char*)Kl + swz(o >> 8, o & 255)) = kr[p];
    }
#pragma unroll
    for (int p = 0; p < 4; ++p) {
      const int dh = p * 32 + (tid >> 4);
      *(bf16x8*)((char*)Vt + swz(dh, (tid & 15) * 16)) = vr[p];
    }
    BAR();  // staged (lgkm only; vmcnt untouched)

    if (c + 1 < NCHUNK) LOADC(c + 1);  // prefetch in flight across QK+softmax+PV

    // ---- S = Q K^T
    f32x4 sacc[8];
    __builtin_amdgcn_s_setprio(1);
#pragma unroll
    for (int nt = 0; nt < 8; ++nt) {
      f32x4 acc = {0.f, 0.f, 0.f, 0.f};
      const int key = nt * 16 + l15;
#pragma unroll
      for (int kb = 0; kb < 4; ++kb) {
        bf16x8 bfr = *(const bf16x8*)((const char*)Kl + swz(key, kb * 64 + lhi * 16));
        acc = __builtin_amdgcn_mfma_f32_16x16x32_bf16(qa[kb], bfr, acc, 0, 0, 0);
      }
      sacc[nt] = acc;
    }
    __builtin_amdgcn_s_setprio(0);

    BAR();  // all waves' QK reads of Kl complete -> safe to overlay P below

    // ---- chunk-local row max over 128 keys
    float mc[4];
#pragma unroll
    for (int r = 0; r < 4; ++r) {
      float m0 = sacc[0][r];
#pragma unroll
      for (int nt = 1; nt < 8; ++nt) m0 = fmaxf(m0, sacc[nt][r]);
      mc[r] = m0;
    }
#pragma unroll
    for (int sh = 1; sh < 16; sh <<= 1)
#pragma unroll
      for (int r = 0; r < 4; ++r)
        mc[r] = fmaxf(mc[r], __shfl_xor(mc[r], sh, 64));

    float esc[4], psum[4];
#pragma unroll
    for (int r = 0; r < 4; ++r) {
      const float mn = fmaxf(m_run[r], mc[r]);
      esc[r] = __expf(m_run[r] - mn);
      m_run[r] = mn;
      psum[r] = 0.f;
    }

    // ---- p = exp(s - m_chunk): accumulate psum and write P straight to LDS
    bf16_t* Pw = Kl + wave * (16 * 128);   // per-wave 4KB slice
#pragma unroll
    for (int nt = 0; nt < 8; ++nt)
#pragma unroll
      for (int r = 0; r < 4; ++r) {
        const float p = __expf(sacc[nt][r] - mc[r]);
        psum[r] += p;
        const int row = lhi * 4 + r;
        *(bf16_t*)((char*)Pw + swz(row, (nt * 16 + l15) * 2)) = (bf16_t)p;
      }
#pragma unroll
    for (int sh = 1; sh < 16; sh <<= 1)
#pragma unroll
      for (int r = 0; r < 4; ++r)
        psum[r] += __shfl_xor(psum[r], sh, 64);
#pragma unroll
    for (int r = 0; r < 4; ++r)
      l_run[r] = l_run[r] * esc[r] + psum[r];
#pragma unroll
    for (int nt = 0; nt < 8; ++nt) {
      f32x4 o = oacc[nt];
      o[0] *= esc[0]; o[1] *= esc[1]; o[2] *= esc[2]; o[3] *= esc[3];
      oacc[nt] = o;
    }

    asm volatile("s_waitcnt lgkmcnt(0)" ::: "memory");  // wave-local P write->read
    __builtin_amdgcn_sched_barrier(0);

    // ---- O += P V
    __builtin_amdgcn_s_setprio(1);
#pragma unroll
    for (int kb = 0; kb < 4; ++kb) {
      bf16x8 pf = *(const bf16x8*)((const char*)Pw + swz(l15, kb * 64 + lhi * 16));
#pragma unroll
      for (int nt = 0; nt < 8; ++nt) {
        const int dh = nt * 16 + l15;
        bf16x8 vf = *(const bf16x8*)((const char*)Vt + swz(dh, kb * 64 + lhi * 16));
        oacc[nt] = __builtin_amdgcn_mfma_f32_16x16x32_bf16(pf, vf, oacc[nt], 0, 0, 0);
      }
    }
    __builtin_amdgcn_s_setprio(0);
  }

  // ---- epilogue: per-wave LDS transpose -> coalesced f32x4 stores
  BAR();  // all PV reads of Kl/Vt done; smem reusable
  {
    char* Ow = smem + wave * 8192;  // 16 rows x 512B
#pragma unroll
    for (int nt = 0; nt < 8; ++nt)
#pragma unroll
      for (int r = 0; r < 4; ++r) {
        const int row = lhi * 4 + r;
        const int colb = (nt * 16 + l15) * 4;
        *(float*)(Ow + row * 512 + (colb ^ ((row & 7) << 4))) =
            oacc[nt][r] / (l_run[r] + 1e-6f);
      }
    asm volatile("s_waitcnt lgkmcnt(0)" ::: "memory");  // wave-local only
    __builtin_amdgcn_sched_barrier(0);
#pragma unroll
    for (int p = 0; p < 8; ++p) {
      const int row = p * 2 + (lane >> 5);
      const int colb = (lane & 31) * 16;
      f32x4 val = *(const f32x4*)(Ow + row * 512 + (colb ^ ((row & 7) << 4)));
      *(f32x4*)((char*)(og + ((size_t)(b * SEQ + qrow0 + row)) * DMODEL + h * DHEAD) + colb) = val;
    }
  }
}

// ---------------- fallback (R2 kernel, proven): used if ws too small ----------------
__global__ __launch_bounds__(512, 2)
void fa_fwd_raw(const float* __restrict__ qg, const float* __restrict__ kg,
                const float* __restrict__ vg, float* __restrict__ og)
{
  __shared__ bf16_t Kl[CHUNK * DHEAD];
  __shared__ bf16_t Vt[DHEAD * CHUNK];
  const int tid = threadIdx.x, wave = tid >> 6, lane = tid & 63;
  const int l15 = lane & 15, lhi = lane >> 4;
  const int b = blockIdx.z, h = blockIdx.y;
  const int qrow0 = blockIdx.x * QBLK + wave * 16;
  bf16x8 qa[4];
  {
    const float* qp = qg + ((size_t)(b * SEQ + qrow0 + l15)) * DMODEL + h * DHEAD;
    const float sc = 1.0f / 128.0f;
#pragma unroll
    for (int kb = 0; kb < 4; ++kb) {
      const float* p8 = qp + kb * 32 + lhi * 8;
      float4 x0 = *(const float4*)p8; float4 x1 = *(const float4*)(p8 + 4);
      bf16x8 a;
      a[0]=(bf16_t)(x0.x*sc); a[1]=(bf16_t)(x0.y*sc); a[2]=(bf16_t)(x0.z*sc); a[3]=(bf16_t)(x0.w*sc);
      a[4]=(bf16_t)(x1.x*sc); a[5]=(bf16_t)(x1.y*sc); a[6]=(bf16_t)(x1.z*sc); a[7]=(bf16_t)(x1.w*sc);
      qa[kb] = a;
    }
  }
  f32x4 oacc[8];
#pragma unroll
  for (int nt = 0; nt < 8; ++nt) { f32x4 z = {0.f,0.f,0.f,0.f}; oacc[nt] = z; }
  float m_run[4] = {-INFINITY,-INFINITY,-INFINITY,-INFINITY};
  float l_run[4] = {0.f,0.f,0.f,0.f};
  const float* kbp = kg + ((size_t)b * SEQ) * DMODEL + h * DHEAD;
  const float* vbp = vg + ((size_t)b * SEQ) * DMODEL + h * DHEAD;
  const int krow16 = tid >> 5, kc4 = (tid & 31) * 4;
  const int vdh = tid & 127, vkg = (tid >> 7) * 8;
  for (int c = 0; c < NCHUNK; ++c) {
    const int key0 = c * CHUNK;
#pragma unroll
    for (int pass = 0; pass < 8; ++pass) {
      const int key = pass * 16 + krow16;
      const float4 x = *(const float4*)(kbp + (size_t)(key0 + key) * DMODEL + kc4);
      bf16x4 y; y[0]=(bf16_t)x.x; y[1]=(bf16_t)x.y; y[2]=(bf16_t)x.z; y[3]=(bf16_t)x.w;
      *(bf16x4*)((char*)Kl + swz(key, kc4 * 2)) = y;
    }
#pragma unroll
    for (int it = 0; it < 4; ++it) {
      const int kb0 = it * 32 + vkg;
      const float* vp = vbp + (size_t)(key0 + kb0) * DMODEL + vdh;
      bf16x8 y;
#pragma unroll
      for (int j = 0; j < 8; ++j) y[j] = (bf16_t)vp[(size_t)j * DMODEL];
      *(bf16x8*)((char*)Vt + swz(vdh, kb0 * 2)) = y;
    }
    __syncthreads();
    f32x4 sacc[8];
#pragma unroll
    for (int nt = 0; nt < 8; ++nt) {
      f32x4 acc = {0.f,0.f,0.f,0.f};
      const int key = nt * 16 + l15;
#pragma unroll
      for (int kb = 0; kb < 4; ++kb) {
        bf16x8 bfr = *(const bf16x8*)((const char*)Kl + swz(key, (kb*32+lhi*8)*2));
        acc = __builtin_amdgcn_mfma_f32_16x16x32_bf16(qa[kb], bfr, acc, 0, 0, 0);
      }
      sacc[nt] = acc;
    }
    __syncthreads();
    float mc[4];
#pragma unroll
    for (int r = 0; r < 4; ++r) {
      float m0 = sacc[0][r];
#pragma unroll
      for (int nt = 1; nt < 8; ++nt) m0 = fmaxf(m0, sacc[nt][r]);
      mc[r] = m0;
    }
#pragma unroll
    for (int sh = 1; sh < 16; sh <<= 1)
#pragma unroll
      for (int r = 0; r < 4; ++r) mc[r] = fmaxf(mc[r], __shfl_xor(mc[r], sh, 64));
    float esc[4], psum[4];
#pragma unroll
    for (int r = 0; r < 4; ++r) {
      const float mn = fmaxf(m_run[r], mc[r]);
      esc[r] = __expf(m_run[r] - mn); m_run[r] = mn; psum[r] = 0.f;
    }
    bf16_t* Pw = Kl + wave * (16 * 128);
#pragma unroll
    for (int nt = 0; nt < 8; ++nt)
#pragma unroll
      for (int r = 0; r < 4; ++r) {
        const float p = __expf(sacc[nt][r] - mc[r]);
        psum[r] += p;
        const int row = lhi * 4 + r;
        *(bf16_t*)((char*)Pw + swz(row, (nt*16+l15)*2)) = (bf16_t)p;
      }
#pragma unroll
    for (int sh = 1; sh < 16; sh <<= 1)
#pragma unroll
      for (int r = 0; r < 4; ++r) psum[r] += __shfl_xor(psum[r], sh, 64);
#pragma unroll
    for (int r = 0; r < 4; ++r) l_run[r] = l_run[r] * esc[r] + psum[r];
#pragma unroll
    for (int nt = 0; nt < 8; ++nt) {
      f32x4 o = oacc[nt];
      o[0]*=esc[0]; o[1]*=esc[1]; o[2]*=esc[2]; o[3]*=esc[3];
      oacc[nt] = o;
    }
    asm volatile("s_waitcnt lgkmcnt(0)" ::: "memory");
    __builtin_amdgcn_sched_barrier(0);
#pragma unroll
    for (int kb = 0; kb < 4; ++kb) {
      bf16x8 pf = *(const bf16x8*)((const char*)Pw + swz(l15, (kb*32+lhi*8)*2));
#pragma unroll
      for (int nt = 0; nt < 8; ++nt) {
        const int dh = nt * 16 + l15;
        bf16x8 vf = *(const bf16x8*)((const char*)Vt + swz(dh, (kb*32+lhi*8)*2));
        oacc[nt] = __builtin_amdgcn_mfma_f32_16x16x32_bf16(pf, vf, oacc[nt], 0, 0, 0);
      }
    }
    __syncthreads();
  }
#pragma unroll
  for (int nt = 0; nt < 8; ++nt)
#pragma unroll
    for (int r = 0; r < 4; ++r) {
      const int row = lhi * 4 + r;
      og[((size_t)(b * SEQ + qrow0 + row)) * DMODEL + h * DHEAD + nt * 16 + l15] =
          oacc[nt][r] / (l_run[r] + 1e-6f);
    }
}

extern "C" void kernel_launch(void* const* d_in, const int* in_sizes, int n_in,
                              void* d_out, int out_size, void* d_ws, size_t ws_size,
                              hipStream_t stream) {
  const float* q = (const float*)d_in[0];
  const float* k = (const float*)d_in[1];
  const float* v = (const float*)d_in[2];
  float* o = (float*)d_out;
  const int B = in_sizes[0] / (SEQ * DMODEL);
  const size_t kv_bytes = (size_t)B * NHEADS * SEQ * DHEAD * 2;  // 33.5MB @ B=2
  dim3 grid(SEQ / QBLK, NHEADS, B);
  if (ws_size >= 2 * kv_bytes) {
    bf16_t* kb = (bf16_t*)d_ws;
    bf16_t* vb = (bf16_t*)((char*)d_ws + kv_bytes);
    const int nthr = (int)(((size_t)B * SEQ * DMODEL) / 8);
    prep_k<<<nthr / 256, 256, 0, stream>>>(k, kb);
    dim3 gv(SEQ / 128, NHEADS, B);
    prep_v<<<gv, 256, 0, stream>>>(v, vb);
    fa_fwd_p<<<grid, 512, 0, stream>>>(q, kb, vb, o);
  } else {
    fa_fwd_raw<<<grid, 512, 0, stream>>>(q, k, v, o);
  }
}

// Round 5
// 353.632 us; speedup vs baseline: 5.9598x; 1.5695x over previous
//
#include <hip/hip_runtime.h>
#include <hip/hip_bf16.h>
#include <stdint.h>

#define SEQ     4096
#define DMODEL  2048
#define NHEADS  16
#define DHEAD   128
#define QBLK    128
#define CHUNK   128
#define NCHUNK  (SEQ / CHUNK)

typedef __bf16 bf16_t;
typedef bf16_t bf16x8 __attribute__((ext_vector_type(8)));
typedef bf16_t bf16x4 __attribute__((ext_vector_type(4)));
typedef float  f32x4  __attribute__((ext_vector_type(4)));

typedef __attribute__((address_space(3))) uint32_t       lds_u32_t;
typedef __attribute__((address_space(1))) const uint32_t glb_u32_t;

static __device__ __forceinline__ void gload16(const void* g, void* l) {
  __builtin_amdgcn_global_load_lds((glb_u32_t*)g, (lds_u32_t*)l, 16, 0, 0);
}

// legacy swizzle for the fallback kernel + epilogue
__device__ __forceinline__ uint32_t swz(int row, int colbyte) {
  return ((uint32_t)(row * 256 + colbyte)) ^ ((uint32_t)(row & 15) << 4);
}

// ---------------- prepass: K -> bf16 head-major [bh][s][128] ----------------
__global__ __launch_bounds__(256)
void prep_k(const float* __restrict__ kk, bf16_t* __restrict__ kb) {
  const size_t e = ((size_t)blockIdx.x * 256 + threadIdx.x) * 8;
  const int dm = (int)(e % DMODEL);
  const int s  = (int)((e / DMODEL) % SEQ);
  const int b  = (int)(e / ((size_t)DMODEL * SEQ));
  float4 x0 = *(const float4*)(kk + e);
  float4 x1 = *(const float4*)(kk + e + 4);
  bf16x8 y;
  y[0]=(bf16_t)x0.x; y[1]=(bf16_t)x0.y; y[2]=(bf16_t)x0.z; y[3]=(bf16_t)x0.w;
  y[4]=(bf16_t)x1.x; y[5]=(bf16_t)x1.y; y[6]=(bf16_t)x1.z; y[7]=(bf16_t)x1.w;
  const size_t out = (((size_t)(b * NHEADS + (dm >> 7)) * SEQ + s) << 7) + (dm & 127);
  *(bf16x8*)(kb + out) = y;
}

// ---------------- prepass: V -> bf16 transposed [bh][dh][s] ----------------
__global__ __launch_bounds__(256)
void prep_v(const float* __restrict__ vv, bf16_t* __restrict__ vb) {
  __shared__ bf16_t T[128 * 132];
  const int t = threadIdx.x;
  const int s0 = blockIdx.x * 128, h = blockIdx.y, b = blockIdx.z;
  const float* src = vv + ((size_t)(b * SEQ + s0)) * DMODEL + h * DHEAD;
#pragma unroll
  for (int p = 0; p < 16; ++p) {
    const int sr = p * 8 + (t >> 5), c4 = (t & 31) * 4;
    float4 x = *(const float4*)(src + (size_t)sr * DMODEL + c4);
    bf16_t* d = T + sr * 132 + c4;
    d[0]=(bf16_t)x.x; d[1]=(bf16_t)x.y; d[2]=(bf16_t)x.z; d[3]=(bf16_t)x.w;
  }
  __syncthreads();
  bf16_t* out = vb + ((size_t)(b * NHEADS + h)) * DHEAD * SEQ;
#pragma unroll
  for (int p = 0; p < 8; ++p) {
    const int d = p * 16 + (t >> 4), sc8 = (t & 15) * 8;
    bf16x8 y;
#pragma unroll
    for (int j = 0; j < 8; ++j) y[j] = T[(sc8 + j) * 132 + d];
    *(bf16x8*)(out + (size_t)d * SEQ + s0 + sc8) = y;
  }
}

// ---------------- main: counted-vmcnt pipelined flash attention ----------------
// Faithful reference quirks: total scale 1/128; p = exp(s - m_chunk) with
// chunk-local max over exactly 128 keys (2 x 64-key tiles); o,l rescaled by
// exp(m_old-m_new); out = o/(l+1e-6). Chunks strictly in order.
//
// Pipeline: K/V staged by global_load_lds (pre-swizzled global source, linear
// LDS dest). 4 x 16KB tile buffers reused in place = time-shifted dbuf:
//   K(c+1) issued after QK(c) reads done; V(c+1) issued after PV(c).
// Counted s_waitcnt vmcnt(4) before use; NO vmcnt(0)/lgkmcnt(0) in the loop.
// Swapped QK^T (mfma(K,Q)) with permuted key-tiles: lane holds exactly the
// PV A-fragment -> P stays in registers, softmax is lane-local.
__global__ __launch_bounds__(512, 2)
void fa_fwd_p(const float* __restrict__ qg, const bf16_t* __restrict__ kbg,
              const bf16_t* __restrict__ vbg, float* __restrict__ og)
{
  __shared__ char smem[65536];
  // layout: KA @0, KB @16K (rows 256B, gxK swizzle)
  //         VA @32K, VB @48K (rows 128B, dh&7 swizzle)

  const int tid  = threadIdx.x;
  const int wave = tid >> 6;
  const int lane = tid & 63;
  const int l15  = lane & 15;
  const int lhi  = lane >> 4;

  // T1: bijective XCD swizzle (nwg = 32*16*B, %8==0)
  const int nwg = gridDim.x * gridDim.y * gridDim.z;
  const int lin = blockIdx.x + gridDim.x * (blockIdx.y + gridDim.y * blockIdx.z);
  const int wg  = (lin % 8) * (nwg / 8) + lin / 8;
  const int bx  = wg % gridDim.x;
  const int h   = (wg / gridDim.x) % NHEADS;
  const int b   = wg / (gridDim.x * NHEADS);
  const int bh  = b * NHEADS + h;
  const int qrow0 = bx * QBLK + wave * 16;

  const bf16_t* kcb = kbg + ((size_t)bh * SEQ) * DHEAD;   // [key][128]
  const bf16_t* vcb = vbg + ((size_t)bh * DHEAD) * SEQ;   // [dh][SEQ]

  // ---- issue helpers: 2 gload16 per wave per tile (16KB tile, 8 waves) ----
  // K tile: LDS linear row = u*32 + wave*4 + (lane>>4), granule gl = lane&15
  //   logical K[row][col] stored at byte row*256 + (col*2 ^ (gxK(row)<<4))
  //   gxK(row) = (row&3) | ((row>>3)&1)<<2  -> source granule = gl ^ gxK
#define ISSUE_K(koff, key0)                                                    \
  {                                                                            \
    _Pragma("unroll")                                                          \
    for (int u = 0; u < 2; ++u) {                                              \
      const int row = u * 32 + wave * 4 + (lane >> 4);                         \
      const int gl  = lane & 15;                                               \
      const int gx  = (row & 3) | (((row >> 3) & 1) << 2);                     \
      gload16(kcb + (size_t)((key0) + row) * 128 + (gl ^ gx) * 8,              \
              smem + (koff) + u * 8192 + wave * 1024);                         \
    }                                                                          \
  }
  // V tile: LDS linear row dh = u*64 + wave*8 + (lane>>3), granule gl = lane&7
  //   logical V^T[dh][key] at byte dh*128 + (key*2 ^ ((dh&7)<<4))
#define ISSUE_V(voff, key0)                                                    \
  {                                                                            \
    _Pragma("unroll")                                                          \
    for (int u = 0; u < 2; ++u) {                                              \
      const int dh = u * 64 + wave * 8 + (lane >> 3);                          \
      const int gl = lane & 7;                                                 \
      gload16(vcb + (size_t)dh * SEQ + (key0) + (gl ^ (dh & 7)) * 8,           \
              smem + (voff) + u * 8192 + wave * 1024);                         \
    }                                                                          \
  }

  // prologue: prefetch chunk 0 (8 gloads outstanding), then Q
  ISSUE_K(0, 0);
  ISSUE_K(16384, 64);
  ISSUE_V(32768, 0);
  ISSUE_V(49152, 64);

  // ---- Q fragments, B-operand layout (col=l15 -> qrow, k=lhi*8+i), scale 1/128
  bf16x8 qa[4];
  {
    const float* qp = qg + ((size_t)(b * SEQ + qrow0 + l15)) * DMODEL + h * DHEAD;
    const float sc = 1.0f / 128.0f;
#pragma unroll
    for (int kb = 0; kb < 4; ++kb) {
      const float* p8 = qp + kb * 32 + lhi * 8;
      float4 x0 = *(const float4*)p8;
      float4 x1 = *(const float4*)(p8 + 4);
      bf16x8 a;
      a[0] = (bf16_t)(x0.x * sc); a[1] = (bf16_t)(x0.y * sc);
      a[2] = (bf16_t)(x0.z * sc); a[3] = (bf16_t)(x0.w * sc);
      a[4] = (bf16_t)(x1.x * sc); a[5] = (bf16_t)(x1.y * sc);
      a[6] = (bf16_t)(x1.z * sc); a[7] = (bf16_t)(x1.w * sc);
      qa[kb] = a;
    }
  }

  f32x4 oacc[8];
#pragma unroll
  for (int nt = 0; nt < 8; ++nt) { f32x4 z = {0.f,0.f,0.f,0.f}; oacc[nt] = z; }
  float m_run = -INFINITY;   // per-lane, qrow = l15 (duplicated over lhi)
  float l_run = 0.f;

  for (int c = 0; c < NCHUNK; ++c) {
    // K_A, K_B landed (they are the oldest of the <=8 outstanding loads)
    asm volatile("s_waitcnt vmcnt(4)\n\ts_barrier" ::: "memory");

    // ---- S = K Q^T on both 64-key tiles (permuted key rows)
    // lane ends up holding S[key = t*64 + kb_l*32 + lhi*8 + half*4 + r][qrow=l15]
    f32x4 sacc[8];
    __builtin_amdgcn_s_setprio(1);
#pragma unroll
    for (int t = 0; t < 2; ++t) {
      const char* Kt = smem + t * 16384;
#pragma unroll
      for (int nl = 0; nl < 4; ++nl) {
        const int rowA = (nl >> 1) * 32 + (l15 >> 2) * 8 + (nl & 1) * 4 + (l15 & 3);
        const int gx   = (rowA & 3) | (((rowA >> 3) & 1) << 2);
        f32x4 acc = {0.f, 0.f, 0.f, 0.f};
#pragma unroll
        for (int j = 0; j < 4; ++j) {
          const uint32_t byte = (uint32_t)(rowA * 256) + ((j * 64 + lhi * 16) ^ (gx << 4));
          bf16x8 kf = *(const bf16x8*)(Kt + byte);
          acc = __builtin_amdgcn_mfma_f32_16x16x32_bf16(kf, qa[j], acc, 0, 0, 0);
        }
        sacc[t * 4 + nl] = acc;
      }
    }
    __builtin_amdgcn_s_setprio(0);

    // all waves done reading K buffers (ds data consumed by MFMAs above)
    asm volatile("s_waitcnt lgkmcnt(0)\n\ts_barrier" ::: "memory");
    if (c + 1 < NCHUNK) {            // prefetch next chunk's K
      ISSUE_K(0, (c + 1) * CHUNK);
      ISSUE_K(16384, (c + 1) * CHUNK + 64);
    }

    // ---- lane-local softmax over this lane's 32 keys + combine lhi groups
    float mc;
    {
      float m0 = sacc[0][0];
#pragma unroll
      for (int i = 0; i < 8; ++i)
#pragma unroll
        for (int r = 0; r < 4; ++r)
          if (i + r) m0 = fmaxf(m0, sacc[i][r]);
      mc = m0;
    }
    mc = fmaxf(mc, __shfl_xor(mc, 16, 64));
    mc = fmaxf(mc, __shfl_xor(mc, 32, 64));

    const float mn = fmaxf(m_run, mc);
    const float e  = __expf(m_run - mn);   // exp(-inf)=0 on first chunk
    m_run = mn;

    // p = exp(s - m_chunk); pack PV A-fragments entirely in registers
    bf16x8 pa[4];
    float ps = 0.f;
#pragma unroll
    for (int nt = 0; nt < 8; ++nt)
#pragma unroll
      for (int r = 0; r < 4; ++r) {
        const float p = __expf(sacc[nt][r] - mc);
        ps += p;
        pa[(nt >> 2) * 2 + ((nt >> 1) & 1)][(nt & 1) * 4 + r] = (bf16_t)p;
      }
    ps += __shfl_xor(ps, 16, 64);
    ps += __shfl_xor(ps, 32, 64);
    l_run = l_run * e + ps;

    // rescale O by e of the row each acc slot belongs to (qrow = lhi*4+r)
#pragma unroll
    for (int r = 0; r < 4; ++r) {
      const float er = __shfl(e, lhi * 4 + r, 16);
#pragma unroll
      for (int nt = 0; nt < 8; ++nt) oacc[nt][r] *= er;
    }

    // V_A, V_B landed (oldest among [V 4, K' 4] outstanding)
    asm volatile("s_waitcnt vmcnt(4)\n\ts_barrier" ::: "memory");

    // ---- O += P V
    __builtin_amdgcn_s_setprio(1);
#pragma unroll
    for (int kv = 0; kv < 4; ++kv) {
      const char* Vt = smem + 32768 + (kv >> 1) * 16384;
#pragma unroll
      for (int nt = 0; nt < 8; ++nt) {
        const int dh = nt * 16 + l15;
        const uint32_t byte = (uint32_t)(dh * 128) +
            (((kv & 1) * 64 + lhi * 16) ^ ((dh & 7) << 4));
        bf16x8 vf = *(const bf16x8*)(Vt + byte);
        oacc[nt] = __builtin_amdgcn_mfma_f32_16x16x32_bf16(pa[kv], vf, oacc[nt], 0, 0, 0);
      }
    }
    __builtin_amdgcn_s_setprio(0);

    // all waves done reading V buffers
    asm volatile("s_waitcnt lgkmcnt(0)\n\ts_barrier" ::: "memory");
    if (c + 1 < NCHUNK) {            // prefetch next chunk's V
      ISSUE_V(32768, (c + 1) * CHUNK);
      ISSUE_V(49152, (c + 1) * CHUNK + 64);
    }
  }

  // ---- epilogue: per-wave LDS transpose -> coalesced f32x4 stores
  {
    const float lr0 = __shfl(l_run, lhi * 4 + 0, 16);
    const float lr1 = __shfl(l_run, lhi * 4 + 1, 16);
    const float lr2 = __shfl(l_run, lhi * 4 + 2, 16);
    const float lr3 = __shfl(l_run, lhi * 4 + 3, 16);
    const float lr[4] = {lr0, lr1, lr2, lr3};
    char* Ow = smem + wave * 8192;  // 16 rows x 512B
#pragma unroll
    for (int nt = 0; nt < 8; ++nt)
#pragma unroll
      for (int r = 0; r < 4; ++r) {
        const int row = lhi * 4 + r;
        const int colb = (nt * 16 + l15) * 4;
        *(float*)(Ow + row * 512 + (colb ^ ((row & 7) << 4))) =
            oacc[nt][r] / (lr[r] + 1e-6f);
      }
    asm volatile("s_waitcnt lgkmcnt(0)" ::: "memory");  // wave-local only
    __builtin_amdgcn_sched_barrier(0);
#pragma unroll
    for (int p = 0; p < 8; ++p) {
      const int row = p * 2 + (lane >> 5);
      const int colb = (lane & 31) * 16;
      f32x4 val = *(const f32x4*)(Ow + row * 512 + (colb ^ ((row & 7) << 4)));
      *(f32x4*)((char*)(og + ((size_t)(b * SEQ + qrow0 + row)) * DMODEL + h * DHEAD) + colb) = val;
    }
  }
#undef ISSUE_K
#undef ISSUE_V
}

// ---------------- fallback (R2-proven): used if ws too small ----------------
__global__ __launch_bounds__(512, 2)
void fa_fwd_raw(const float* __restrict__ qg, const float* __restrict__ kg,
                const float* __restrict__ vg, float* __restrict__ og)
{
  __shared__ bf16_t Kl[CHUNK * DHEAD];
  __shared__ bf16_t Vt[DHEAD * CHUNK];
  const int tid = threadIdx.x, wave = tid >> 6, lane = tid & 63;
  const int l15 = lane & 15, lhi = lane >> 4;
  const int b = blockIdx.z, h = blockIdx.y;
  const int qrow0 = blockIdx.x * QBLK + wave * 16;
  bf16x8 qa[4];
  {
    const float* qp = qg + ((size_t)(b * SEQ + qrow0 + l15)) * DMODEL + h * DHEAD;
    const float sc = 1.0f / 128.0f;
#pragma unroll
    for (int kb = 0; kb < 4; ++kb) {
      const float* p8 = qp + kb * 32 + lhi * 8;
      float4 x0 = *(const float4*)p8; float4 x1 = *(const float4*)(p8 + 4);
      bf16x8 a;
      a[0]=(bf16_t)(x0.x*sc); a[1]=(bf16_t)(x0.y*sc); a[2]=(bf16_t)(x0.z*sc); a[3]=(bf16_t)(x0.w*sc);
      a[4]=(bf16_t)(x1.x*sc); a[5]=(bf16_t)(x1.y*sc); a[6]=(bf16_t)(x1.z*sc); a[7]=(bf16_t)(x1.w*sc);
      qa[kb] = a;
    }
  }
  f32x4 oacc[8];
#pragma unroll
  for (int nt = 0; nt < 8; ++nt) { f32x4 z = {0.f,0.f,0.f,0.f}; oacc[nt] = z; }
  float m_run[4] = {-INFINITY,-INFINITY,-INFINITY,-INFINITY};
  float l_run[4] = {0.f,0.f,0.f,0.f};
  const float* kbp = kg + ((size_t)b * SEQ) * DMODEL + h * DHEAD;
  const float* vbp = vg + ((size_t)b * SEQ) * DMODEL + h * DHEAD;
  const int krow16 = tid >> 5, kc4 = (tid & 31) * 4;
  const int vdh = tid & 127, vkg = (tid >> 7) * 8;
  for (int c = 0; c < NCHUNK; ++c) {
    const int key0 = c * CHUNK;
#pragma unroll
    for (int pass = 0; pass < 8; ++pass) {
      const int key = pass * 16 + krow16;
      const float4 x = *(const float4*)(kbp + (size_t)(key0 + key) * DMODEL + kc4);
      bf16x4 y; y[0]=(bf16_t)x.x; y[1]=(bf16_t)x.y; y[2]=(bf16_t)x.z; y[3]=(bf16_t)x.w;
      *(bf16x4*)((char*)Kl + swz(key, kc4 * 2)) = y;
    }
#pragma unroll
    for (int it = 0; it < 4; ++it) {
      const int kb0 = it * 32 + vkg;
      const float* vp = vbp + (size_t)(key0 + kb0) * DMODEL + vdh;
      bf16x8 y;
#pragma unroll
      for (int j = 0; j < 8; ++j) y[j] = (bf16_t)vp[(size_t)j * DMODEL];
      *(bf16x8*)((char*)Vt + swz(vdh, kb0 * 2)) = y;
    }
    __syncthreads();
    f32x4 sacc[8];
#pragma unroll
    for (int nt = 0; nt < 8; ++nt) {
      f32x4 acc = {0.f,0.f,0.f,0.f};
      const int key = nt * 16 + l15;
#pragma unroll
      for (int kb = 0; kb < 4; ++kb) {
        bf16x8 bfr = *(const bf16x8*)((const char*)Kl + swz(key, (kb*32+lhi*8)*2));
        acc = __builtin_amdgcn_mfma_f32_16x16x32_bf16(qa[kb], bfr, acc, 0, 0, 0);
      }
      sacc[nt] = acc;
    }
    __syncthreads();
    float mc[4];
#pragma unroll
    for (int r = 0; r < 4; ++r) {
      float m0 = sacc[0][r];
#pragma unroll
      for (int nt = 1; nt < 8; ++nt) m0 = fmaxf(m0, sacc[nt][r]);
      mc[r] = m0;
    }
#pragma unroll
    for (int sh = 1; sh < 16; sh <<= 1)
#pragma unroll
      for (int r = 0; r < 4; ++r) mc[r] = fmaxf(mc[r], __shfl_xor(mc[r], sh, 64));
    float esc[4], psum[4];
#pragma unroll
    for (int r = 0; r < 4; ++r) {
      const float mn = fmaxf(m_run[r], mc[r]);
      esc[r] = __expf(m_run[r] - mn); m_run[r] = mn; psum[r] = 0.f;
    }
    bf16_t* Pw = Kl + wave * (16 * 128);
#pragma unroll
    for (int nt = 0; nt < 8; ++nt)
#pragma unroll
      for (int r = 0; r < 4; ++r) {
        const float p = __expf(sacc[nt][r] - mc[r]);
        psum[r] += p;
        const int row = lhi * 4 + r;
        *(bf16_t*)((char*)Pw + swz(row, (nt*16+l15)*2)) = (bf16_t)p;
      }
#pragma unroll
    for (int sh = 1; sh < 16; sh <<= 1)
#pragma unroll
      for (int r = 0; r < 4; ++r) psum[r] += __shfl_xor(psum[r], sh, 64);
#pragma unroll
    for (int r = 0; r < 4; ++r) l_run[r] = l_run[r] * esc[r] + psum[r];
#pragma unroll
    for (int nt = 0; nt < 8; ++nt) {
      f32x4 o = oacc[nt];
      o[0]*=esc[0]; o[1]*=esc[1]; o[2]*=esc[2]; o[3]*=esc[3];
      oacc[nt] = o;
    }
    asm volatile("s_waitcnt lgkmcnt(0)" ::: "memory");
    __builtin_amdgcn_sched_barrier(0);
#pragma unroll
    for (int kb = 0; kb < 4; ++kb) {
      bf16x8 pf = *(const bf16x8*)((const char*)Pw + swz(l15, (kb*32+lhi*8)*2));
#pragma unroll
      for (int nt = 0; nt < 8; ++nt) {
        const int dh = nt * 16 + l15;
        bf16x8 vf = *(const bf16x8*)((const char*)Vt + swz(dh, (kb*32+lhi*8)*2));
        oacc[nt] = __builtin_amdgcn_mfma_f32_16x16x32_bf16(pf, vf, oacc[nt], 0, 0, 0);
      }
    }
    __syncthreads();
  }
#pragma unroll
  for (int nt = 0; nt < 8; ++nt)
#pragma unroll
    for (int r = 0; r < 4; ++r) {
      const int row = lhi * 4 + r;
      og[((size_t)(b * SEQ + qrow0 + row)) * DMODEL + h * DHEAD + nt * 16 + l15] =
          oacc[nt][r] / (l_run[r] + 1e-6f);
    }
}

extern "C" void kernel_launch(void* const* d_in, const int* in_sizes, int n_in,
                              void* d_out, int out_size, void* d_ws, size_t ws_size,
                              hipStream_t stream) {
  const float* q = (const float*)d_in[0];
  const float* k = (const float*)d_in[1];
  const float* v = (const float*)d_in[2];
  float* o = (float*)d_out;
  const int B = in_sizes[0] / (SEQ * DMODEL);
  const size_t kv_bytes = (size_t)B * NHEADS * SEQ * DHEAD * 2;  // 33.5MB @ B=2
  dim3 grid(SEQ / QBLK, NHEADS, B);
  if (ws_size >= 2 * kv_bytes) {
    bf16_t* kb = (bf16_t*)d_ws;
    bf16_t* vb = (bf16_t*)((char*)d_ws + kv_bytes);
    const int nthr = (int)(((size_t)B * SEQ * DMODEL) / 8);
    prep_k<<<nthr / 256, 256, 0, stream>>>(k, kb);
    dim3 gv(SEQ / 128, NHEADS, B);
    prep_v<<<gv, 256, 0, stream>>>(v, vb);
    fa_fwd_p<<<grid, 512, 0, stream>>>(q, kb, vb, o);
  } else {
    fa_fwd_raw<<<grid, 512, 0, stream>>>(q, k, v, o);
  }
}

// Round 6
// 339.508 us; speedup vs baseline: 6.2077x; 1.0416x over previous
//
#include <hip/hip_runtime.h>
#include <hip/hip_bf16.h>
#include <stdint.h>

#define SEQ     4096
#define DMODEL  2048
#define NHEADS  16
#define DHEAD   128
#define QBLK    128
#define CHUNK   128
#define NCHUNK  (SEQ / CHUNK)

typedef __bf16 bf16_t;
typedef bf16_t bf16x8 __attribute__((ext_vector_type(8)));
typedef bf16_t bf16x4 __attribute__((ext_vector_type(4)));
typedef float  f32x4  __attribute__((ext_vector_type(4)));

typedef __attribute__((address_space(3))) uint32_t       lds_u32_t;
typedef __attribute__((address_space(1))) const uint32_t glb_u32_t;

static __device__ __forceinline__ void gload16(const void* g, void* l) {
  __builtin_amdgcn_global_load_lds((glb_u32_t*)g, (lds_u32_t*)l, 16, 0, 0);
}

// native exp2 (v_exp_f32); s_nop guards the 1-cycle trans->VALU hazard
static __device__ __forceinline__ float exp2_fast(float x) {
  float r;
  asm("v_exp_f32 %0, %1\n\ts_nop 0" : "=v"(r) : "v"(x));
  return r;
}

// legacy swizzle for the fallback kernel + epilogue
__device__ __forceinline__ uint32_t swz(int row, int colbyte) {
  return ((uint32_t)(row * 256 + colbyte)) ^ ((uint32_t)(row & 15) << 4);
}

// ---------------- prepass: K -> bf16 head-major [bh][s][128] ----------------
__global__ __launch_bounds__(256)
void prep_k(const float* __restrict__ kk, bf16_t* __restrict__ kb) {
  const size_t e = ((size_t)blockIdx.x * 256 + threadIdx.x) * 8;
  const int dm = (int)(e % DMODEL);
  const int s  = (int)((e / DMODEL) % SEQ);
  const int b  = (int)(e / ((size_t)DMODEL * SEQ));
  float4 x0 = *(const float4*)(kk + e);
  float4 x1 = *(const float4*)(kk + e + 4);
  bf16x8 y;
  y[0]=(bf16_t)x0.x; y[1]=(bf16_t)x0.y; y[2]=(bf16_t)x0.z; y[3]=(bf16_t)x0.w;
  y[4]=(bf16_t)x1.x; y[5]=(bf16_t)x1.y; y[6]=(bf16_t)x1.z; y[7]=(bf16_t)x1.w;
  const size_t out = (((size_t)(b * NHEADS + (dm >> 7)) * SEQ + s) << 7) + (dm & 127);
  *(bf16x8*)(kb + out) = y;
}

// ---------------- prepass: V -> bf16 transposed [bh][dh][s] ----------------
__global__ __launch_bounds__(256)
void prep_v(const float* __restrict__ vv, bf16_t* __restrict__ vb) {
  __shared__ bf16_t T[128 * 132];
  const int t = threadIdx.x;
  const int s0 = blockIdx.x * 128, h = blockIdx.y, b = blockIdx.z;
  const float* src = vv + ((size_t)(b * SEQ + s0)) * DMODEL + h * DHEAD;
#pragma unroll
  for (int p = 0; p < 16; ++p) {
    const int sr = p * 8 + (t >> 5), c4 = (t & 31) * 4;
    float4 x = *(const float4*)(src + (size_t)sr * DMODEL + c4);
    bf16_t* d = T + sr * 132 + c4;
    d[0]=(bf16_t)x.x; d[1]=(bf16_t)x.y; d[2]=(bf16_t)x.z; d[3]=(bf16_t)x.w;
  }
  __syncthreads();
  bf16_t* out = vb + ((size_t)(b * NHEADS + h)) * DHEAD * SEQ;
#pragma unroll
  for (int p = 0; p < 8; ++p) {
    const int d = p * 16 + (t >> 4), sc8 = (t & 15) * 8;
    bf16x8 y;
#pragma unroll
    for (int j = 0; j < 8; ++j) y[j] = T[(sc8 + j) * 132 + d];
    *(bf16x8*)(out + (size_t)d * SEQ + s0 + sc8) = y;
  }
}

// ---------------- main: 2-barrier pipelined flash attention ----------------
// Faithful reference quirks: total scale 1/128; p = exp(s - m_chunk) with
// chunk-local max over exactly 128 keys; o,l rescaled by exp(m_old-m_new);
// out = o/(l+1e-6). Chunks strictly in order.
//
// Softmax runs in the log2 domain: Q pre-scaled by log2(e)/128, so
// exp(s - m) == exp2(sacc - mc) -- one native v_exp_f32 per element.
//
// Loop has exactly 2 barriers/chunk; at each, vmcnt(0) is an EXACT counted
// wait (the only outstanding loads are the ones needed next):
//   QK(c) -> [wait V(c), bar] -> issue K(c+1) -> softmax -> PV(c)
//         -> [wait K(c+1), bar] -> issue V(c+1)
__global__ __launch_bounds__(512, 2)
void fa_fwd_p(const float* __restrict__ qg, const bf16_t* __restrict__ kbg,
              const bf16_t* __restrict__ vbg, float* __restrict__ og)
{
  __shared__ char smem[65536];
  // layout: KA @0, KB @16K (rows 256B, gxK swizzle)
  //         VA @32K, VB @48K (rows 128B, dh&7 swizzle)

  const int tid  = threadIdx.x;
  const int wave = tid >> 6;
  const int lane = tid & 63;
  const int l15  = lane & 15;
  const int lhi  = lane >> 4;

  // T1: bijective XCD swizzle (nwg = 32*16*B, %8==0)
  const int nwg = gridDim.x * gridDim.y * gridDim.z;
  const int lin = blockIdx.x + gridDim.x * (blockIdx.y + gridDim.y * blockIdx.z);
  const int wg  = (lin % 8) * (nwg / 8) + lin / 8;
  const int bx  = wg % gridDim.x;
  const int h   = (wg / gridDim.x) % NHEADS;
  const int b   = wg / (gridDim.x * NHEADS);
  const int bh  = b * NHEADS + h;
  const int qrow0 = bx * QBLK + wave * 16;

  const bf16_t* kcb = kbg + ((size_t)bh * SEQ) * DHEAD;   // [key][128]
  const bf16_t* vcb = vbg + ((size_t)bh * DHEAD) * SEQ;   // [dh][SEQ]

#define ISSUE_K(koff, key0)                                                    \
  {                                                                            \
    _Pragma("unroll")                                                          \
    for (int u = 0; u < 2; ++u) {                                              \
      const int row = u * 32 + wave * 4 + (lane >> 4);                         \
      const int gl  = lane & 15;                                               \
      const int gx  = (row & 3) | (((row >> 3) & 1) << 2);                     \
      gload16(kcb + (size_t)((key0) + row) * 128 + (gl ^ gx) * 8,              \
              smem + (koff) + u * 8192 + wave * 1024);                         \
    }                                                                          \
  }
#define ISSUE_V(voff, key0)                                                    \
  {                                                                            \
    _Pragma("unroll")                                                          \
    for (int u = 0; u < 2; ++u) {                                              \
      const int dh = u * 64 + wave * 8 + (lane >> 3);                          \
      const int gl = lane & 7;                                                 \
      gload16(vcb + (size_t)dh * SEQ + (key0) + (gl ^ (dh & 7)) * 8,           \
              smem + (voff) + u * 8192 + wave * 1024);                         \
    }                                                                          \
  }

  // prologue: prefetch chunk 0 (K first, then V -> vmcnt retires in order)
  ISSUE_K(0, 0);
  ISSUE_K(16384, 64);
  ISSUE_V(32768, 0);
  ISSUE_V(49152, 64);

  // ---- Q fragments, B-operand layout; scale = log2(e)/128 (log2-domain scores)
  bf16x8 qa[4];
  {
    const float* qp = qg + ((size_t)(b * SEQ + qrow0 + l15)) * DMODEL + h * DHEAD;
    const float sc = 1.4426950408889634f / 128.0f;
#pragma unroll
    for (int kb = 0; kb < 4; ++kb) {
      const float* p8 = qp + kb * 32 + lhi * 8;
      float4 x0 = *(const float4*)p8;
      float4 x1 = *(const float4*)(p8 + 4);
      bf16x8 a;
      a[0] = (bf16_t)(x0.x * sc); a[1] = (bf16_t)(x0.y * sc);
      a[2] = (bf16_t)(x0.z * sc); a[3] = (bf16_t)(x0.w * sc);
      a[4] = (bf16_t)(x1.x * sc); a[5] = (bf16_t)(x1.y * sc);
      a[6] = (bf16_t)(x1.z * sc); a[7] = (bf16_t)(x1.w * sc);
      qa[kb] = a;
    }
  }

  f32x4 oacc[8];
#pragma unroll
  for (int nt = 0; nt < 8; ++nt) { f32x4 z = {0.f,0.f,0.f,0.f}; oacc[nt] = z; }
  float m_run = -INFINITY;   // log2-domain; per-lane, qrow = l15
  float l_run = 0.f;

  // K(0) landed (oldest 4 of the <=8 outstanding)
  asm volatile("s_waitcnt vmcnt(4)\n\ts_barrier" ::: "memory");

  for (int c = 0; c < NCHUNK; ++c) {
    // ---- S = K Q^T on both 64-key tiles (permuted key rows)
    f32x4 sacc[8];
    __builtin_amdgcn_s_setprio(1);
#pragma unroll
    for (int t = 0; t < 2; ++t) {
      const char* Kt = smem + t * 16384;
#pragma unroll
      for (int nl = 0; nl < 4; ++nl) {
        const int rowA = (nl >> 1) * 32 + (l15 >> 2) * 8 + (nl & 1) * 4 + (l15 & 3);
        const int gx   = (rowA & 3) | (((rowA >> 3) & 1) << 2);
        f32x4 acc = {0.f, 0.f, 0.f, 0.f};
#pragma unroll
        for (int j = 0; j < 4; ++j) {
          const uint32_t byte = (uint32_t)(rowA * 256) + ((j * 64 + lhi * 16) ^ (gx << 4));
          bf16x8 kf = *(const bf16x8*)(Kt + byte);
          acc = __builtin_amdgcn_mfma_f32_16x16x32_bf16(kf, qa[j], acc, 0, 0, 0);
        }
        sacc[t * 4 + nl] = acc;
      }
    }
    __builtin_amdgcn_s_setprio(0);

    // V(c) landed (only outstanding loads) + all waves' QK reads done
    asm volatile("s_waitcnt vmcnt(0) lgkmcnt(0)\n\ts_barrier" ::: "memory");
    if (c + 1 < NCHUNK) {            // prefetch next chunk's K into K bufs
      ISSUE_K(0, (c + 1) * CHUNK);
      ISSUE_K(16384, (c + 1) * CHUNK + 64);
    }

    // ---- lane-local softmax over this lane's 32 keys (log2 domain)
    float mc;
    {
      float m0 = sacc[0][0];
#pragma unroll
      for (int i = 0; i < 8; ++i)
#pragma unroll
        for (int r = 0; r < 4; ++r)
          if (i + r) m0 = fmaxf(m0, sacc[i][r]);
      mc = m0;
    }
    mc = fmaxf(mc, __shfl_xor(mc, 16, 64));
    mc = fmaxf(mc, __shfl_xor(mc, 32, 64));

    const float mn = fmaxf(m_run, mc);
    const float e  = exp2_fast(m_run - mn);   // exp2(-inf)=0 on first chunk
    m_run = mn;

    // p = exp2(sacc - mc); pack PV A-fragments entirely in registers
    bf16x8 pa[4];
    float ps = 0.f;
#pragma unroll
    for (int nt = 0; nt < 8; ++nt)
#pragma unroll
      for (int r = 0; r < 4; ++r) {
        const float p = exp2_fast(sacc[nt][r] - mc);
        ps += p;
        pa[(nt >> 2) * 2 + ((nt >> 1) & 1)][(nt & 1) * 4 + r] = (bf16_t)p;
      }
    ps += __shfl_xor(ps, 16, 64);
    ps += __shfl_xor(ps, 32, 64);
    l_run = l_run * e + ps;

    // rescale O by e of the row each acc slot belongs to (qrow = lhi*4+r)
#pragma unroll
    for (int r = 0; r < 4; ++r) {
      const float er = __shfl(e, lhi * 4 + r, 16);
#pragma unroll
      for (int nt = 0; nt < 8; ++nt) oacc[nt][r] *= er;
    }

    // ---- O += P V   (V(c) already waited at the barrier above)
    __builtin_amdgcn_s_setprio(1);
#pragma unroll
    for (int kv = 0; kv < 4; ++kv) {
      const char* Vt = smem + 32768 + (kv >> 1) * 16384;
#pragma unroll
      for (int nt = 0; nt < 8; ++nt) {
        const int dh = nt * 16 + l15;
        const uint32_t byte = (uint32_t)(dh * 128) +
            (((kv & 1) * 64 + lhi * 16) ^ ((dh & 7) << 4));
        bf16x8 vf = *(const bf16x8*)(Vt + byte);
        oacc[nt] = __builtin_amdgcn_mfma_f32_16x16x32_bf16(pa[kv], vf, oacc[nt], 0, 0, 0);
      }
    }
    __builtin_amdgcn_s_setprio(0);

    // K(c+1) landed (only outstanding loads) + all waves' PV reads done
    asm volatile("s_waitcnt vmcnt(0) lgkmcnt(0)\n\ts_barrier" ::: "memory");
    if (c + 1 < NCHUNK) {            // prefetch next chunk's V into V bufs
      ISSUE_V(32768, (c + 1) * CHUNK);
      ISSUE_V(49152, (c + 1) * CHUNK + 64);
    }
  }

  // ---- epilogue: per-wave LDS transpose -> coalesced f32x4 stores
  {
    const float lr0 = __shfl(l_run, lhi * 4 + 0, 16);
    const float lr1 = __shfl(l_run, lhi * 4 + 1, 16);
    const float lr2 = __shfl(l_run, lhi * 4 + 2, 16);
    const float lr3 = __shfl(l_run, lhi * 4 + 3, 16);
    const float lr[4] = {lr0, lr1, lr2, lr3};
    char* Ow = smem + wave * 8192;  // 16 rows x 512B
#pragma unroll
    for (int nt = 0; nt < 8; ++nt)
#pragma unroll
      for (int r = 0; r < 4; ++r) {
        const int row = lhi * 4 + r;
        const int colb = (nt * 16 + l15) * 4;
        *(float*)(Ow + row * 512 + (colb ^ ((row & 7) << 4))) =
            oacc[nt][r] / (lr[r] + 1e-6f);
      }
    asm volatile("s_waitcnt lgkmcnt(0)" ::: "memory");  // wave-local only
    __builtin_amdgcn_sched_barrier(0);
#pragma unroll
    for (int p = 0; p < 8; ++p) {
      const int row = p * 2 + (lane >> 5);
      const int colb = (lane & 31) * 16;
      f32x4 val = *(const f32x4*)(Ow + row * 512 + (colb ^ ((row & 7) << 4)));
      *(f32x4*)((char*)(og + ((size_t)(b * SEQ + qrow0 + row)) * DMODEL + h * DHEAD) + colb) = val;
    }
  }
#undef ISSUE_K
#undef ISSUE_V
}

// ---------------- fallback (R2-proven): used if ws too small ----------------
__global__ __launch_bounds__(512, 2)
void fa_fwd_raw(const float* __restrict__ qg, const float* __restrict__ kg,
                const float* __restrict__ vg, float* __restrict__ og)
{
  __shared__ bf16_t Kl[CHUNK * DHEAD];
  __shared__ bf16_t Vt[DHEAD * CHUNK];
  const int tid = threadIdx.x, wave = tid >> 6, lane = tid & 63;
  const int l15 = lane & 15, lhi = lane >> 4;
  const int b = blockIdx.z, h = blockIdx.y;
  const int qrow0 = blockIdx.x * QBLK + wave * 16;
  bf16x8 qa[4];
  {
    const float* qp = qg + ((size_t)(b * SEQ + qrow0 + l15)) * DMODEL + h * DHEAD;
    const float sc = 1.0f / 128.0f;
#pragma unroll
    for (int kb = 0; kb < 4; ++kb) {
      const float* p8 = qp + kb * 32 + lhi * 8;
      float4 x0 = *(const float4*)p8; float4 x1 = *(const float4*)(p8 + 4);
      bf16x8 a;
      a[0]=(bf16_t)(x0.x*sc); a[1]=(bf16_t)(x0.y*sc); a[2]=(bf16_t)(x0.z*sc); a[3]=(bf16_t)(x0.w*sc);
      a[4]=(bf16_t)(x1.x*sc); a[5]=(bf16_t)(x1.y*sc); a[6]=(bf16_t)(x1.z*sc); a[7]=(bf16_t)(x1.w*sc);
      qa[kb] = a;
    }
  }
  f32x4 oacc[8];
#pragma unroll
  for (int nt = 0; nt < 8; ++nt) { f32x4 z = {0.f,0.f,0.f,0.f}; oacc[nt] = z; }
  float m_run[4] = {-INFINITY,-INFINITY,-INFINITY,-INFINITY};
  float l_run[4] = {0.f,0.f,0.f,0.f};
  const float* kbp = kg + ((size_t)b * SEQ) * DMODEL + h * DHEAD;
  const float* vbp = vg + ((size_t)b * SEQ) * DMODEL + h * DHEAD;
  const int krow16 = tid >> 5, kc4 = (tid & 31) * 4;
  const int vdh = tid & 127, vkg = (tid >> 7) * 8;
  for (int c = 0; c < NCHUNK; ++c) {
    const int key0 = c * CHUNK;
#pragma unroll
    for (int pass = 0; pass < 8; ++pass) {
      const int key = pass * 16 + krow16;
      const float4 x = *(const float4*)(kbp + (size_t)(key0 + key) * DMODEL + kc4);
      bf16x4 y; y[0]=(bf16_t)x.x; y[1]=(bf16_t)x.y; y[2]=(bf16_t)x.z; y[3]=(bf16_t)x.w;
      *(bf16x4*)((char*)Kl + swz(key, kc4 * 2)) = y;
    }
#pragma unroll
    for (int it = 0; it < 4; ++it) {
      const int kb0 = it * 32 + vkg;
      const float* vp = vbp + (size_t)(key0 + kb0) * DMODEL + vdh;
      bf16x8 y;
#pragma unroll
      for (int j = 0; j < 8; ++j) y[j] = (bf16_t)vp[(size_t)j * DMODEL];
      *(bf16x8*)((char*)Vt + swz(vdh, kb0 * 2)) = y;
    }
    __syncthreads();
    f32x4 sacc[8];
#pragma unroll
    for (int nt = 0; nt < 8; ++nt) {
      f32x4 acc = {0.f,0.f,0.f,0.f};
      const int key = nt * 16 + l15;
#pragma unroll
      for (int kb = 0; kb < 4; ++kb) {
        bf16x8 bfr = *(const bf16x8*)((const char*)Kl + swz(key, (kb*32+lhi*8)*2));
        acc = __builtin_amdgcn_mfma_f32_16x16x32_bf16(qa[kb], bfr, acc, 0, 0, 0);
      }
      sacc[nt] = acc;
    }
    __syncthreads();
    float mc[4];
#pragma unroll
    for (int r = 0; r < 4; ++r) {
      float m0 = sacc[0][r];
#pragma unroll
      for (int nt = 1; nt < 8; ++nt) m0 = fmaxf(m0, sacc[nt][r]);
      mc[r] = m0;
    }
#pragma unroll
    for (int sh = 1; sh < 16; sh <<= 1)
#pragma unroll
      for (int r = 0; r < 4; ++r) mc[r] = fmaxf(mc[r], __shfl_xor(mc[r], sh, 64));
    float esc[4], psum[4];
#pragma unroll
    for (int r = 0; r < 4; ++r) {
      const float mn = fmaxf(m_run[r], mc[r]);
      esc[r] = __expf(m_run[r] - mn); m_run[r] = mn; psum[r] = 0.f;
    }
    bf16_t* Pw = Kl + wave * (16 * 128);
#pragma unroll
    for (int nt = 0; nt < 8; ++nt)
#pragma unroll
      for (int r = 0; r < 4; ++r) {
        const float p = __expf(sacc[nt][r] - mc[r]);
        psum[r] += p;
        const int row = lhi * 4 + r;
        *(bf16_t*)((char*)Pw + swz(row, (nt*16+l15)*2)) = (bf16_t)p;
      }
#pragma unroll
    for (int sh = 1; sh < 16; sh <<= 1)
#pragma unroll
      for (int r = 0; r < 4; ++r) psum[r] += __shfl_xor(psum[r], sh, 64);
#pragma unroll
    for (int r = 0; r < 4; ++r) l_run[r] = l_run[r] * esc[r] + psum[r];
#pragma unroll
    for (int nt = 0; nt < 8; ++nt) {
      f32x4 o = oacc[nt];
      o[0]*=esc[0]; o[1]*=esc[1]; o[2]*=esc[2]; o[3]*=esc[3];
      oacc[nt] = o;
    }
    asm volatile("s_waitcnt lgkmcnt(0)" ::: "memory");
    __builtin_amdgcn_sched_barrier(0);
#pragma unroll
    for (int kb = 0; kb < 4; ++kb) {
      bf16x8 pf = *(const bf16x8*)((const char*)Pw + swz(l15, (kb*32+lhi*8)*2));
#pragma unroll
      for (int nt = 0; nt < 8; ++nt) {
        const int dh = nt * 16 + l15;
        bf16x8 vf = *(const bf16x8*)((const char*)Vt + swz(dh, (kb*32+lhi*8)*2));
        oacc[nt] = __builtin_amdgcn_mfma_f32_16x16x32_bf16(pf, vf, oacc[nt], 0, 0, 0);
      }
    }
    __syncthreads();
  }
#pragma unroll
  for (int nt = 0; nt < 8; ++nt)
#pragma unroll
    for (int r = 0; r < 4; ++r) {
      const int row = lhi * 4 + r;
      og[((size_t)(b * SEQ + qrow0 + row)) * DMODEL + h * DHEAD + nt * 16 + l15] =
          oacc[nt][r] / (l_run[r] + 1e-6f);
    }
}

extern "C" void kernel_launch(void* const* d_in, const int* in_sizes, int n_in,
                              void* d_out, int out_size, void* d_ws, size_t ws_size,
                              hipStream_t stream) {
  const float* q = (const float*)d_in[0];
  const float* k = (const float*)d_in[1];
  const float* v = (const float*)d_in[2];
  float* o = (float*)d_out;
  const int B = in_sizes[0] / (SEQ * DMODEL);
  const size_t kv_bytes = (size_t)B * NHEADS * SEQ * DHEAD * 2;  // 33.5MB @ B=2
  dim3 grid(SEQ / QBLK, NHEADS, B);
  if (ws_size >= 2 * kv_bytes) {
    bf16_t* kb = (bf16_t*)d_ws;
    bf16_t* vb = (bf16_t*)((char*)d_ws + kv_bytes);
    const int nthr = (int)(((size_t)B * SEQ * DMODEL) / 8);
    prep_k<<<nthr / 256, 256, 0, stream>>>(k, kb);
    dim3 gv(SEQ / 128, NHEADS, B);
    prep_v<<<gv, 256, 0, stream>>>(v, vb);
    fa_fwd_p<<<grid, 512, 0, stream>>>(q, kb, vb, o);
  } else {
    fa_fwd_raw<<<grid, 512, 0, stream>>>(q, k, v, o);
  }
}

// Round 7
// 335.675 us; speedup vs baseline: 6.2786x; 1.0114x over previous
//
#include <hip/hip_runtime.h>
#include <hip/hip_bf16.h>
#include <stdint.h>

#define SEQ     4096
#define DMODEL  2048
#define NHEADS  16
#define DHEAD   128
#define QBLK    256
#define CHUNK   128
#define NCHUNK  (SEQ / CHUNK)

typedef __bf16 bf16_t;
typedef bf16_t bf16x8 __attribute__((ext_vector_type(8)));
typedef bf16_t bf16x4 __attribute__((ext_vector_type(4)));
typedef float  f32x4  __attribute__((ext_vector_type(4)));

typedef __attribute__((address_space(3))) uint32_t       lds_u32_t;
typedef __attribute__((address_space(1))) const uint32_t glb_u32_t;

static __device__ __forceinline__ void gload16(const void* g, void* l) {
  __builtin_amdgcn_global_load_lds((glb_u32_t*)g, (lds_u32_t*)l, 16, 0, 0);
}

// native exp2 (v_exp_f32); s_nop guards the trans->VALU hazard
static __device__ __forceinline__ float exp2_fast(float x) {
  float r;
  asm("v_exp_f32 %0, %1\n\ts_nop 0" : "=v"(r) : "v"(x));
  return r;
}

// legacy swizzle for the fallback kernel
__device__ __forceinline__ uint32_t swz(int row, int colbyte) {
  return ((uint32_t)(row * 256 + colbyte)) ^ ((uint32_t)(row & 15) << 4);
}

// ---------------- prepass: K -> bf16 head-major [bh][s][128] ----------------
__global__ __launch_bounds__(256)
void prep_k(const float* __restrict__ kk, bf16_t* __restrict__ kb) {
  const size_t e = ((size_t)blockIdx.x * 256 + threadIdx.x) * 8;
  const int dm = (int)(e % DMODEL);
  const int s  = (int)((e / DMODEL) % SEQ);
  const int b  = (int)(e / ((size_t)DMODEL * SEQ));
  float4 x0 = *(const float4*)(kk + e);
  float4 x1 = *(const float4*)(kk + e + 4);
  bf16x8 y;
  y[0]=(bf16_t)x0.x; y[1]=(bf16_t)x0.y; y[2]=(bf16_t)x0.z; y[3]=(bf16_t)x0.w;
  y[4]=(bf16_t)x1.x; y[5]=(bf16_t)x1.y; y[6]=(bf16_t)x1.z; y[7]=(bf16_t)x1.w;
  const size_t out = (((size_t)(b * NHEADS + (dm >> 7)) * SEQ + s) << 7) + (dm & 127);
  *(bf16x8*)(kb + out) = y;
}

// ---------------- prepass: V -> bf16 transposed [bh][dh][s] ----------------
__global__ __launch_bounds__(256)
void prep_v(const float* __restrict__ vv, bf16_t* __restrict__ vb) {
  __shared__ bf16_t T[128 * 132];
  const int t = threadIdx.x;
  const int s0 = blockIdx.x * 128, h = blockIdx.y, b = blockIdx.z;
  const float* src = vv + ((size_t)(b * SEQ + s0)) * DMODEL + h * DHEAD;
#pragma unroll
  for (int p = 0; p < 16; ++p) {
    const int sr = p * 8 + (t >> 5), c4 = (t & 31) * 4;
    float4 x = *(const float4*)(src + (size_t)sr * DMODEL + c4);
    bf16_t* d = T + sr * 132 + c4;
    d[0]=(bf16_t)x.x; d[1]=(bf16_t)x.y; d[2]=(bf16_t)x.z; d[3]=(bf16_t)x.w;
  }
  __syncthreads();
  bf16_t* out = vb + ((size_t)(b * NHEADS + h)) * DHEAD * SEQ;
#pragma unroll
  for (int p = 0; p < 8; ++p) {
    const int d = p * 16 + (t >> 4), sc8 = (t & 15) * 8;
    bf16x8 y;
#pragma unroll
    for (int j = 0; j < 8; ++j) y[j] = T[(sc8 + j) * 132 + d];
    *(bf16x8*)(out + (size_t)d * SEQ + s0 + sc8) = y;
  }
}

// ---------------- main: 2-barrier pipelined FA, 32 q-rows/wave ----------------
// Faithful reference quirks: total scale 1/128 (here log2e/128, log2-domain);
// p = exp(s - m_chunk) with chunk-local max over exactly 128 keys; o,l rescaled
// by exp(m_old-m_new); out = o/(l+1e-6). Chunks strictly in order.
//
// Each wave owns 32 q-rows (2 halves of 16): every K/V LDS read feeds TWO
// MFMAs -> total LDS read traffic halves vs 16 q/wave (LDS BW was the R6
// bottleneck: 17.2 GB -> 8.6 GB). Conflict-free 4-bit XOR swizzles:
//   K rows 256B, gx(row) = (row&3)|(((row>>3)&3)<<2)  (= l15 on read)
//   V rows 256B [dh][128 keys], gx = dh&15             (= l15 on read)
// Loop: QK(c) -> [vmcnt0,bar] -> issue K(c+1) -> softmax -> PV(c)
//       -> [vmcnt0,bar] -> issue V(c+1).  Waits are exact counted drains.
__global__ __launch_bounds__(512, 1)
void fa_fwd_p(const float* __restrict__ qg, const bf16_t* __restrict__ kbg,
              const bf16_t* __restrict__ vbg, float* __restrict__ og)
{
  __shared__ char smem[65536];
  // KA @0 (keys 0-63), KB @16K (keys 64-127), V @32K (32KB, keys 0-127)

  const int tid  = threadIdx.x;
  const int wave = tid >> 6;
  const int lane = tid & 63;
  const int l15  = lane & 15;
  const int lhi  = lane >> 4;

  // T1: bijective XCD swizzle (nwg = 16*16*B = 512 @ B=2, %8==0)
  const int nwg = gridDim.x * gridDim.y * gridDim.z;
  const int lin = blockIdx.x + gridDim.x * (blockIdx.y + gridDim.y * blockIdx.z);
  const int wg  = (lin % 8) * (nwg / 8) + lin / 8;
  const int bx  = wg % gridDim.x;
  const int h   = (wg / gridDim.x) % NHEADS;
  const int b   = wg / (gridDim.x * NHEADS);
  const int bh  = b * NHEADS + h;
  const int qrow0 = bx * QBLK + wave * 32;

  const bf16_t* kcb = kbg + ((size_t)bh * SEQ) * DHEAD;   // [key][128]
  const bf16_t* vcb = vbg + ((size_t)bh * DHEAD) * SEQ;   // [dh][SEQ]

  // K tile stage: 2 loads/wave; row = u*32 + wave*4 + (lane>>4), granule lane&15
#define ISSUE_K(koff, key0)                                                    \
  {                                                                            \
    _Pragma("unroll")                                                          \
    for (int u = 0; u < 2; ++u) {                                              \
      const int row = u * 32 + wave * 4 + (lane >> 4);                         \
      const int gx  = (row & 3) | (((row >> 3) & 3) << 2);                     \
      gload16(kcb + (size_t)((key0) + row) * 128 + (((lane & 15) ^ gx) * 8),   \
              smem + (koff) + u * 8192 + wave * 1024);                         \
    }                                                                          \
  }
  // V stage: 4 loads/wave; dh = u*32 + wave*4 + (lane>>4), granule lane&15
#define ISSUE_V(key0)                                                          \
  {                                                                            \
    _Pragma("unroll")                                                          \
    for (int u = 0; u < 4; ++u) {                                              \
      const int dh = u * 32 + wave * 4 + (lane >> 4);                          \
      gload16(vcb + (size_t)dh * SEQ + (key0) + (((lane & 15) ^ (dh & 15)) * 8),\
              smem + 32768 + u * 8192 + wave * 1024);                          \
    }                                                                          \
  }

  // prologue: prefetch chunk 0 (K first, then V; vmcnt retires in order)
  ISSUE_K(0, 0);
  ISSUE_K(16384, 64);
  ISSUE_V(0);

  // ---- Q fragments, 2 halves, B-operand layout; scale = log2(e)/128
  bf16x8 qa[8];
  {
    const float sc = 1.4426950408889634f / 128.0f;
#pragma unroll
    for (int h2 = 0; h2 < 2; ++h2) {
      const float* qp =
          qg + ((size_t)(b * SEQ + qrow0 + h2 * 16 + l15)) * DMODEL + h * DHEAD;
#pragma unroll
      for (int kb = 0; kb < 4; ++kb) {
        const float* p8 = qp + kb * 32 + lhi * 8;
        float4 x0 = *(const float4*)p8;
        float4 x1 = *(const float4*)(p8 + 4);
        bf16x8 a;
        a[0] = (bf16_t)(x0.x * sc); a[1] = (bf16_t)(x0.y * sc);
        a[2] = (bf16_t)(x0.z * sc); a[3] = (bf16_t)(x0.w * sc);
        a[4] = (bf16_t)(x1.x * sc); a[5] = (bf16_t)(x1.y * sc);
        a[6] = (bf16_t)(x1.z * sc); a[7] = (bf16_t)(x1.w * sc);
        qa[h2 * 4 + kb] = a;
      }
    }
  }

  f32x4 oacc[16];
#pragma unroll
  for (int nt = 0; nt < 16; ++nt) { f32x4 z = {0.f,0.f,0.f,0.f}; oacc[nt] = z; }
  float m_run0 = -INFINITY, l_run0 = 0.f;   // log2-domain, per lane (qrow=l15)
  float m_run1 = -INFINITY, l_run1 = 0.f;

  // K(0) landed (oldest 4 of the 8 outstanding)
  asm volatile("s_waitcnt vmcnt(4)\n\ts_barrier" ::: "memory");

  for (int c = 0; c < NCHUNK; ++c) {
    // ---- S = K Q^T, both halves share each kf read (permuted key rows)
    f32x4 s0[8], s1[8];
    __builtin_amdgcn_s_setprio(1);
#pragma unroll
    for (int t = 0; t < 2; ++t) {
      const char* Kt = smem + t * 16384;
#pragma unroll
      for (int nl = 0; nl < 4; ++nl) {
        const int rowA = (nl >> 1) * 32 + (l15 >> 2) * 8 + (nl & 1) * 4 + (l15 & 3);
        const int gx   = (rowA & 3) | (((rowA >> 3) & 3) << 2);  // == l15
        f32x4 a0 = {0.f, 0.f, 0.f, 0.f};
        f32x4 a1 = {0.f, 0.f, 0.f, 0.f};
#pragma unroll
        for (int j = 0; j < 4; ++j) {
          const uint32_t byte = (uint32_t)(rowA * 256) + ((j * 64 + lhi * 16) ^ (gx << 4));
          bf16x8 kf = *(const bf16x8*)(Kt + byte);
          a0 = __builtin_amdgcn_mfma_f32_16x16x32_bf16(kf, qa[j], a0, 0, 0, 0);
          a1 = __builtin_amdgcn_mfma_f32_16x16x32_bf16(kf, qa[4 + j], a1, 0, 0, 0);
        }
        s0[t * 4 + nl] = a0;
        s1[t * 4 + nl] = a1;
      }
    }
    __builtin_amdgcn_s_setprio(0);

    // V(c) landed (only outstanding) + all waves' QK reads done
    asm volatile("s_waitcnt vmcnt(0) lgkmcnt(0)\n\ts_barrier" ::: "memory");
    if (c + 1 < NCHUNK) {
      ISSUE_K(0, (c + 1) * CHUNK);
      ISSUE_K(16384, (c + 1) * CHUNK + 64);
    }

    // ---- softmax per half (log2 domain); exact skip of rescale when e==1
    bf16x8 pa0[4], pa1[4];
#define SOFTMAX_HALF(SA, PA, MRUN, LRUN, OBASE)                                \
    {                                                                          \
      float mc = SA[0][0];                                                     \
      _Pragma("unroll")                                                        \
      for (int i = 0; i < 8; ++i)                                              \
        _Pragma("unroll")                                                      \
        for (int r = 0; r < 4; ++r)                                            \
          if (i + r) mc = fmaxf(mc, SA[i][r]);                                 \
      mc = fmaxf(mc, __shfl_xor(mc, 16, 64));                                  \
      mc = fmaxf(mc, __shfl_xor(mc, 32, 64));                                  \
      const bool skip = __all(mc <= MRUN);                                     \
      const float mn = fmaxf(MRUN, mc);                                        \
      const float e  = exp2_fast(MRUN - mn);                                   \
      MRUN = mn;                                                               \
      float ps = 0.f;                                                          \
      _Pragma("unroll")                                                        \
      for (int nt = 0; nt < 8; ++nt)                                           \
        _Pragma("unroll")                                                      \
        for (int r = 0; r < 4; ++r) {                                          \
          const float p = exp2_fast(SA[nt][r] - mc);                           \
          ps += p;                                                             \
          PA[(nt >> 2) * 2 + ((nt >> 1) & 1)][(nt & 1) * 4 + r] = (bf16_t)p;   \
        }                                                                      \
      ps += __shfl_xor(ps, 16, 64);                                            \
      ps += __shfl_xor(ps, 32, 64);                                            \
      if (skip) {                                                              \
        LRUN += ps;                                                            \
      } else {                                                                 \
        LRUN = LRUN * e + ps;                                                  \
        _Pragma("unroll")                                                      \
        for (int r = 0; r < 4; ++r) {                                          \
          const float er = __shfl(e, lhi * 4 + r, 16);                         \
          _Pragma("unroll")                                                    \
          for (int nt = 0; nt < 8; ++nt) oacc[(OBASE) + nt][r] *= er;          \
        }                                                                      \
      }                                                                        \
    }
    SOFTMAX_HALF(s0, pa0, m_run0, l_run0, 0)
    SOFTMAX_HALF(s1, pa1, m_run1, l_run1, 8)
#undef SOFTMAX_HALF

    // ---- O += P V, both halves share each vf read
    __builtin_amdgcn_s_setprio(1);
#pragma unroll
    for (int kv = 0; kv < 4; ++kv) {
#pragma unroll
      for (int nt = 0; nt < 8; ++nt) {
        const int dh = nt * 16 + l15;
        const uint32_t byte = (uint32_t)(32768 + dh * 256) +
            (((uint32_t)(kv * 64 + lhi * 16)) ^ ((dh & 15) << 4));
        bf16x8 vf = *(const bf16x8*)(smem + byte);
        oacc[nt]     = __builtin_amdgcn_mfma_f32_16x16x32_bf16(pa0[kv], vf, oacc[nt], 0, 0, 0);
        oacc[8 + nt] = __builtin_amdgcn_mfma_f32_16x16x32_bf16(pa1[kv], vf, oacc[8 + nt], 0, 0, 0);
      }
    }
    __builtin_amdgcn_s_setprio(0);

    // K(c+1) landed (only outstanding) + all waves' PV reads done
    asm volatile("s_waitcnt vmcnt(0) lgkmcnt(0)\n\ts_barrier" ::: "memory");
    if (c + 1 < NCHUNK) ISSUE_V((c + 1) * CHUNK);
  }

  // ---- epilogue: per-wave LDS transpose -> coalesced f32x4 stores, 2 passes
  {
    char* Ow = smem + wave * 8192;  // 16 rows x 512B per pass
#pragma unroll
    for (int h2 = 0; h2 < 2; ++h2) {
      const float lrl = h2 ? l_run1 : l_run0;
      float lr[4];
#pragma unroll
      for (int r = 0; r < 4; ++r) lr[r] = __shfl(lrl, lhi * 4 + r, 16);
#pragma unroll
      for (int nt = 0; nt < 8; ++nt)
#pragma unroll
        for (int r = 0; r < 4; ++r) {
          const int row = lhi * 4 + r;
          const int colb = (nt * 16 + l15) * 4;
          *(float*)(Ow + row * 512 + (colb ^ ((row & 7) << 4))) =
              oacc[h2 * 8 + nt][r] / (lr[r] + 1e-6f);
        }
      asm volatile("s_waitcnt lgkmcnt(0)" ::: "memory");  // wave-local only
      __builtin_amdgcn_sched_barrier(0);
#pragma unroll
      for (int p = 0; p < 8; ++p) {
        const int row = p * 2 + (lane >> 5);
        const int colb = (lane & 31) * 16;
        f32x4 val = *(const f32x4*)(Ow + row * 512 + (colb ^ ((row & 7) << 4)));
        *(f32x4*)((char*)(og + ((size_t)(b * SEQ + qrow0 + h2 * 16 + row)) * DMODEL +
                          h * DHEAD) + colb) = val;
      }
      asm volatile("s_waitcnt lgkmcnt(0)" ::: "memory");  // reads done before reuse
      __builtin_amdgcn_sched_barrier(0);
    }
  }
#undef ISSUE_K
#undef ISSUE_V
}

// ---------------- fallback (R2-proven): used if ws too small ----------------
__global__ __launch_bounds__(512, 2)
void fa_fwd_raw(const float* __restrict__ qg, const float* __restrict__ kg,
                const float* __restrict__ vg, float* __restrict__ og)
{
  __shared__ bf16_t Kl[CHUNK * DHEAD];
  __shared__ bf16_t Vt[DHEAD * CHUNK];
  const int tid = threadIdx.x, wave = tid >> 6, lane = tid & 63;
  const int l15 = lane & 15, lhi = lane >> 4;
  const int b = blockIdx.z, h = blockIdx.y;
  const int qrow0 = blockIdx.x * 128 + wave * 16;
  bf16x8 qa[4];
  {
    const float* qp = qg + ((size_t)(b * SEQ + qrow0 + l15)) * DMODEL + h * DHEAD;
    const float sc = 1.0f / 128.0f;
#pragma unroll
    for (int kb = 0; kb < 4; ++kb) {
      const float* p8 = qp + kb * 32 + lhi * 8;
      float4 x0 = *(const float4*)p8; float4 x1 = *(const float4*)(p8 + 4);
      bf16x8 a;
      a[0]=(bf16_t)(x0.x*sc); a[1]=(bf16_t)(x0.y*sc); a[2]=(bf16_t)(x0.z*sc); a[3]=(bf16_t)(x0.w*sc);
      a[4]=(bf16_t)(x1.x*sc); a[5]=(bf16_t)(x1.y*sc); a[6]=(bf16_t)(x1.z*sc); a[7]=(bf16_t)(x1.w*sc);
      qa[kb] = a;
    }
  }
  f32x4 oacc[8];
#pragma unroll
  for (int nt = 0; nt < 8; ++nt) { f32x4 z = {0.f,0.f,0.f,0.f}; oacc[nt] = z; }
  float m_run[4] = {-INFINITY,-INFINITY,-INFINITY,-INFINITY};
  float l_run[4] = {0.f,0.f,0.f,0.f};
  const float* kbp = kg + ((size_t)b * SEQ) * DMODEL + h * DHEAD;
  const float* vbp = vg + ((size_t)b * SEQ) * DMODEL + h * DHEAD;
  const int krow16 = tid >> 5, kc4 = (tid & 31) * 4;
  const int vdh = tid & 127, vkg = (tid >> 7) * 8;
  for (int c = 0; c < NCHUNK; ++c) {
    const int key0 = c * CHUNK;
#pragma unroll
    for (int pass = 0; pass < 8; ++pass) {
      const int key = pass * 16 + krow16;
      const float4 x = *(const float4*)(kbp + (size_t)(key0 + key) * DMODEL + kc4);
      bf16x4 y; y[0]=(bf16_t)x.x; y[1]=(bf16_t)x.y; y[2]=(bf16_t)x.z; y[3]=(bf16_t)x.w;
      *(bf16x4*)((char*)Kl + swz(key, kc4 * 2)) = y;
    }
#pragma unroll
    for (int it = 0; it < 4; ++it) {
      const int kb0 = it * 32 + vkg;
      const float* vp = vbp + (size_t)(key0 + kb0) * DMODEL + vdh;
      bf16x8 y;
#pragma unroll
      for (int j = 0; j < 8; ++j) y[j] = (bf16_t)vp[(size_t)j * DMODEL];
      *(bf16x8*)((char*)Vt + swz(vdh, kb0 * 2)) = y;
    }
    __syncthreads();
    f32x4 sacc[8];
#pragma unroll
    for (int nt = 0; nt < 8; ++nt) {
      f32x4 acc = {0.f,0.f,0.f,0.f};
      const int key = nt * 16 + l15;
#pragma unroll
      for (int kb = 0; kb < 4; ++kb) {
        bf16x8 bfr = *(const bf16x8*)((const char*)Kl + swz(key, (kb*32+lhi*8)*2));
        acc = __builtin_amdgcn_mfma_f32_16x16x32_bf16(qa[kb], bfr, acc, 0, 0, 0);
      }
      sacc[nt] = acc;
    }
    __syncthreads();
    float mc[4];
#pragma unroll
    for (int r = 0; r < 4; ++r) {
      float m0 = sacc[0][r];
#pragma unroll
      for (int nt = 1; nt < 8; ++nt) m0 = fmaxf(m0, sacc[nt][r]);
      mc[r] = m0;
    }
#pragma unroll
    for (int sh = 1; sh < 16; sh <<= 1)
#pragma unroll
      for (int r = 0; r < 4; ++r) mc[r] = fmaxf(mc[r], __shfl_xor(mc[r], sh, 64));
    float esc[4], psum[4];
#pragma unroll
    for (int r = 0; r < 4; ++r) {
      const float mn = fmaxf(m_run[r], mc[r]);
      esc[r] = __expf(m_run[r] - mn); m_run[r] = mn; psum[r] = 0.f;
    }
    bf16_t* Pw = Kl + wave * (16 * 128);
#pragma unroll
    for (int nt = 0; nt < 8; ++nt)
#pragma unroll
      for (int r = 0; r < 4; ++r) {
        const float p = __expf(sacc[nt][r] - mc[r]);
        psum[r] += p;
        const int row = lhi * 4 + r;
        *(bf16_t*)((char*)Pw + swz(row, (nt*16+l15)*2)) = (bf16_t)p;
      }
#pragma unroll
    for (int sh = 1; sh < 16; sh <<= 1)
#pragma unroll
      for (int r = 0; r < 4; ++r) psum[r] += __shfl_xor(psum[r], sh, 64);
#pragma unroll
    for (int r = 0; r < 4; ++r) l_run[r] = l_run[r] * esc[r] + psum[r];
#pragma unroll
    for (int nt = 0; nt < 8; ++nt) {
      f32x4 o = oacc[nt];
      o[0]*=esc[0]; o[1]*=esc[1]; o[2]*=esc[2]; o[3]*=esc[3];
      oacc[nt] = o;
    }
    asm volatile("s_waitcnt lgkmcnt(0)" ::: "memory");
    __builtin_amdgcn_sched_barrier(0);
#pragma unroll
    for (int kb = 0; kb < 4; ++kb) {
      bf16x8 pf = *(const bf16x8*)((const char*)Pw + swz(l15, (kb*32+lhi*8)*2));
#pragma unroll
      for (int nt = 0; nt < 8; ++nt) {
        const int dh = nt * 16 + l15;
        bf16x8 vf = *(const bf16x8*)((const char*)Vt + swz(dh, (kb*32+lhi*8)*2));
        oacc[nt] = __builtin_amdgcn_mfma_f32_16x16x32_bf16(pf, vf, oacc[nt], 0, 0, 0);
      }
    }
    __syncthreads();
  }
#pragma unroll
  for (int nt = 0; nt < 8; ++nt)
#pragma unroll
    for (int r = 0; r < 4; ++r) {
      const int row = lhi * 4 + r;
      og[((size_t)(b * SEQ + qrow0 + row)) * DMODEL + h * DHEAD + nt * 16 + l15] =
          oacc[nt][r] / (l_run[r] + 1e-6f);
    }
}

extern "C" void kernel_launch(void* const* d_in, const int* in_sizes, int n_in,
                              void* d_out, int out_size, void* d_ws, size_t ws_size,
                              hipStream_t stream) {
  const float* q = (const float*)d_in[0];
  const float* k = (const float*)d_in[1];
  const float* v = (const float*)d_in[2];
  float* o = (float*)d_out;
  const int B = in_sizes[0] / (SEQ * DMODEL);
  const size_t kv_bytes = (size_t)B * NHEADS * SEQ * DHEAD * 2;  // 33.5MB @ B=2
  if (ws_size >= 2 * kv_bytes) {
    bf16_t* kb = (bf16_t*)d_ws;
    bf16_t* vb = (bf16_t*)((char*)d_ws + kv_bytes);
    const int nthr = (int)(((size_t)B * SEQ * DMODEL) / 8);
    prep_k<<<nthr / 256, 256, 0, stream>>>(k, kb);
    dim3 gv(SEQ / 128, NHEADS, B);
    prep_v<<<gv, 256, 0, stream>>>(v, vb);
    dim3 grid(SEQ / QBLK, NHEADS, B);
    fa_fwd_p<<<grid, 512, 0, stream>>>(q, kb, vb, o);
  } else {
    dim3 grid(SEQ / 128, NHEADS, B);
    fa_fwd_raw<<<grid, 512, 0, stream>>>(q, k, v, o);
  }
}